// Round 6
// baseline (643.739 us; speedup 1.0000x reference)
//
#include <hip/hip_runtime.h>

#define GN 50000      // nodes
#define GE 800000     // edges per graph
#define HID 128
#define OUTC 64
#define NB 196        // scan blocks per graph: ceil(50000/256)
#define NREG (GN / 8) // 6250 nodes per XCD-owned region
#define BSH 5         // 32 nodes per bucket
#define NBUCK 1563    // ceil(50000/32)

// workspace layout (float element offsets)
#define OFF_H1    0            // 6,400,000 f  (x@W1)
#define OFF_H2    6400000      // 3,200,000 f  (relu(bn(hidden))@W2) -- aliased: bucket buffers
#define OFF_DINV1 9600000      // 50,000
#define OFF_DINV2 9650000      // 50,000
#define OFF_ROW1  9700000      // 50,001 int
#define OFF_ROW2  9750004      // 50,001 int
#define OFF_CUR1  9800008      // 50,000 int
#define OFF_CUR2  9850008      // 50,000 int
#define OFF_CNT1  9900008      // 50,000 int   -- memset region start
#define OFF_CNT2  9950008      // 50,000 int
#define OFF_BN    10000008     // 512 f: sum@0 sumsq@128 scale@256 shift@384
#define OFF_SRC1  10000520     // 800,000 int
#define OFF_SRC2  10800520     // 800,000 int
#define OFF_BSUM  11600520     // 2*NB int  (per-block sums, both graphs)
#define OFF_BOFS  11601032     // 2*NB int  (scanned block offsets)
#define OFF_BCUR1 11601424     // NBUCK int (bucket cursors, graph 1)
#define OFF_BCUR2 11602987     // NBUCK int (graph 2)

__global__ __launch_bounds__(256) void count_kernel(const int* __restrict__ e1,
    const int* __restrict__ e2, int* __restrict__ cnt1, int* __restrict__ cnt2) {
  int i = blockIdx.x * 256 + threadIdx.x;
  if (i < GE) {
    atomicAdd(&cnt1[e1[GE + i]], 1);   // dst of graph 1
    atomicAdd(&cnt2[e2[GE + i]], 1);   // dst of graph 2
  }
}

// stage A: per-block sums of cnt. grid = 2*NB blocks; blockIdx.x >= NB -> graph 2
__global__ __launch_bounds__(256) void scanA_kernel(const int* __restrict__ cnt1,
    const int* __restrict__ cnt2, int* __restrict__ bsum) {
  __shared__ int lds[256];
  int b = blockIdx.x;
  int g = (b >= NB) ? 1 : 0;
  int lb = b - g * NB;
  const int* cnt = g ? cnt2 : cnt1;
  int idx = lb * 256 + threadIdx.x;
  int v = (idx < GN) ? cnt[idx] : 0;
  lds[threadIdx.x] = v;
  __syncthreads();
  for (int off = 128; off > 0; off >>= 1) {
    if (threadIdx.x < off) lds[threadIdx.x] += lds[threadIdx.x + off];
    __syncthreads();
  }
  if (threadIdx.x == 0) bsum[b] = lds[0];
}

// stage B: 1 block, exclusive-scan the NB block-sums for each graph; write totals to row[GN]
__global__ __launch_bounds__(256) void scanB_kernel(const int* __restrict__ bsum,
    int* __restrict__ bofs, int* __restrict__ row1, int* __restrict__ row2) {
  __shared__ int lds[256];
  int t = threadIdx.x;
  for (int g = 0; g < 2; ++g) {
    int v = (t < NB) ? bsum[g * NB + t] : 0;
    int orig = v;
    lds[t] = v;
    __syncthreads();
    for (int off = 1; off < 256; off <<= 1) {
      int u = (t >= off) ? lds[t - off] : 0;
      __syncthreads();
      lds[t] += u;
      __syncthreads();
    }
    if (t < NB) bofs[g * NB + t] = lds[t] - orig;   // exclusive
    if (t == NB - 1) { if (g) row2[GN] = lds[t]; else row1[GN] = lds[t]; }
    __syncthreads();
  }
}

// stage C: per-block local exclusive scan + block offset -> row/cur; dinv = rsqrt(1+cnt);
// seed bucket cursors with row[bucket_start]
__global__ __launch_bounds__(256) void scanC_kernel(const int* __restrict__ cnt1,
    const int* __restrict__ cnt2, const int* __restrict__ bofs,
    int* __restrict__ row1, int* __restrict__ cur1, float* __restrict__ dinv1,
    int* __restrict__ row2, int* __restrict__ cur2, float* __restrict__ dinv2,
    int* __restrict__ bcur1, int* __restrict__ bcur2) {
  __shared__ int lds[256];
  int b = blockIdx.x;
  int g = (b >= NB) ? 1 : 0;
  int lb = b - g * NB;
  const int* cnt = g ? cnt2 : cnt1;
  int* row = g ? row2 : row1;
  int* cur = g ? cur2 : cur1;
  float* dinv = g ? dinv2 : dinv1;
  int* bcur = g ? bcur2 : bcur1;
  int t = threadIdx.x;
  int idx = lb * 256 + t;
  int v = (idx < GN) ? cnt[idx] : 0;
  lds[t] = v;
  __syncthreads();
  for (int off = 1; off < 256; off <<= 1) {
    int u = (t >= off) ? lds[t - off] : 0;
    __syncthreads();
    lds[t] += u;
    __syncthreads();
  }
  if (idx < GN) {
    int e = bofs[b] + lds[t] - v;   // exclusive prefix
    row[idx] = e;
    cur[idx] = e;
    dinv[idx] = rsqrtf(1.0f + (float)v);
    if ((idx & 31) == 0) bcur[idx >> BSH] = e;
  }
}

// phase 1: XCD-pinned bucket append. Group k = blockIdx.x & 7 scans ALL edges, keeps
// dst in its node region, appends packed (src | ldst<<16) to bucket tails. One XCD per
// bucket (no cross-XCD line sharing) + sequential tail (temporally compact line fill).
__global__ __launch_bounds__(256) void bucket_scatter_kernel(const int* __restrict__ e1,
    const int* __restrict__ e2, int* __restrict__ bcur1, int* __restrict__ bcur2,
    int* __restrict__ pb1, int* __restrict__ pb2) {
  int g = blockIdx.y;
  const int* e = g ? e2 : e1;
  int* bcur = g ? bcur2 : bcur1;
  int* pb = g ? pb2 : pb1;
  int lo = (blockIdx.x & 7) * NREG;
  int start = (blockIdx.x >> 3) * 256 + threadIdx.x;   // 128 blocks/group x 256 threads
  for (int i = start; i < GE; i += 128 * 256) {
    int d = e[GE + i];
    if ((unsigned)(d - lo) < (unsigned)NREG) {
      int s = e[i];
      int p = atomicAdd(&bcur[d >> BSH], 1);
      pb[p] = s | ((d & 31) << 16);   // src < 50000 < 2^16
    }
  }
}

// phase 2: one wave per bucket; entries for bucket k occupy [row[32k], row[32k+32]).
// Scatter within the bucket's ~2KB CSR span, single CU -> compact writes.
__global__ __launch_bounds__(256) void bucket_fill_kernel(const int* __restrict__ pb1,
    const int* __restrict__ pb2, const int* __restrict__ row1, const int* __restrict__ row2,
    int* __restrict__ cur1, int* __restrict__ cur2,
    int* __restrict__ src1, int* __restrict__ src2) {
  int g = blockIdx.y;
  const int* pb = g ? pb2 : pb1;
  const int* row = g ? row2 : row1;
  int* cur = g ? cur2 : cur1;
  int* src = g ? src2 : src1;
  int wave = (blockIdx.x * 256 + threadIdx.x) >> 6;
  int lane = threadIdx.x & 63;
  if (wave >= NBUCK) return;
  int lo = wave << BSH;
  int hi = lo + 32; if (hi > GN) hi = GN;
  int base = row[lo], end = row[hi];
  for (int i = base + lane; i < end; i += 64) {
    int w = pb[i];
    int d = lo + (w >> 16);
    int s = w & 0xFFFF;
    int p = atomicAdd(&cur[d], 1);
    src[p] = s;
  }
}

// C[M,128] = A[M,128] @ B[128,128]; block tile 32 rows x 64 cols (blockIdx.y selects col half)
__global__ __launch_bounds__(256) void gemm1_kernel(const float* __restrict__ A,
    const float* __restrict__ B, float* __restrict__ C) {
  __shared__ __align__(16) float wlds[128 * 64];
  __shared__ __align__(16) float alds[32 * 128];
  int t = threadIdx.x;
  int row0 = blockIdx.x * 32;
  int cb = blockIdx.y * 64;
  for (int i = t; i < 128 * 16; i += 256) {        // W tile: 128 rows x 16 float4
    int k = i >> 4, c4 = i & 15;
    ((float4*)wlds)[i] = ((const float4*)B)[k * 32 + (cb >> 2) + c4];
  }
  for (int i = t; i < 1024; i += 256) {            // A tile: 32 rows x 32 float4
    int r = i >> 5, c4 = i & 31;
    int gr = row0 + r;
    ((float4*)alds)[i] = (gr < GN) ? ((const float4*)A)[(size_t)gr * 32 + c4]
                                   : make_float4(0.f, 0.f, 0.f, 0.f);
  }
  __syncthreads();
  int j0 = (t & 15) * 4;
  int r0 = (t >> 4) * 2;
  float4 acc0 = {0, 0, 0, 0}, acc1 = {0, 0, 0, 0};
  #pragma unroll 8
  for (int k = 0; k < 128; ++k) {
    float4 w = *(const float4*)&wlds[k * 64 + j0];
    float a0 = alds[r0 * 128 + k];
    float a1 = alds[(r0 + 1) * 128 + k];
    acc0.x += a0 * w.x; acc0.y += a0 * w.y; acc0.z += a0 * w.z; acc0.w += a0 * w.w;
    acc1.x += a1 * w.x; acc1.y += a1 * w.y; acc1.z += a1 * w.z; acc1.w += a1 * w.w;
  }
  int gr0 = row0 + r0;
  if (gr0 < GN)     *(float4*)&C[(size_t)gr0 * 128 + cb + j0] = acc0;
  if (gr0 + 1 < GN) *(float4*)&C[(size_t)(gr0 + 1) * 128 + cb + j0] = acc1;
}

// C[M,64] = relu(bn(A[M,128])) @ B[128,64]
__global__ __launch_bounds__(256) void gemm2_kernel(const float* __restrict__ A,
    const float* __restrict__ B, const float* __restrict__ scale,
    const float* __restrict__ shift, float* __restrict__ C) {
  __shared__ __align__(16) float wlds[128 * 64];
  __shared__ __align__(16) float alds[32 * 128];
  __shared__ float sc[128], sh[128];
  int t = threadIdx.x;
  if (t < 128) { sc[t] = scale[t]; sh[t] = shift[t]; }
  int row0 = blockIdx.x * 32;
  for (int i = t; i < 128 * 16; i += 256)
    ((float4*)wlds)[i] = ((const float4*)B)[i];
  __syncthreads();   // sc/sh ready before prologue
  for (int i = t; i < 1024; i += 256) {
    int r = i >> 5, c4 = i & 31;
    int gr = row0 + r;
    float4 v = (gr < GN) ? ((const float4*)A)[(size_t)gr * 32 + c4]
                         : make_float4(0.f, 0.f, 0.f, 0.f);
    int c = c4 * 4;
    v.x = fmaxf(fmaf(v.x, sc[c],     sh[c]),     0.f);
    v.y = fmaxf(fmaf(v.y, sc[c + 1], sh[c + 1]), 0.f);
    v.z = fmaxf(fmaf(v.z, sc[c + 2], sh[c + 2]), 0.f);
    v.w = fmaxf(fmaf(v.w, sc[c + 3], sh[c + 3]), 0.f);
    ((float4*)alds)[i] = v;
  }
  __syncthreads();
  int j0 = (t & 15) * 4;
  int r0 = (t >> 4) * 2;
  float4 acc0 = {0, 0, 0, 0}, acc1 = {0, 0, 0, 0};
  #pragma unroll 8
  for (int k = 0; k < 128; ++k) {
    float4 w = *(const float4*)&wlds[k * 64 + j0];
    float a0 = alds[r0 * 128 + k];
    float a1 = alds[(r0 + 1) * 128 + k];
    acc0.x += a0 * w.x; acc0.y += a0 * w.y; acc0.z += a0 * w.z; acc0.w += a0 * w.w;
    acc1.x += a1 * w.x; acc1.y += a1 * w.y; acc1.z += a1 * w.z; acc1.w += a1 * w.w;
  }
  int gr0 = row0 + r0;
  if (gr0 < GN)     *(float4*)&C[(size_t)gr0 * 64 + j0] = acc0;
  if (gr0 + 1 < GN) *(float4*)&C[(size_t)(gr0 + 1) * 64 + j0] = acc1;
}

// wave-per-node gather, 4x unrolled for MLP:
// hidden[d] = dinv[d]*(dinv[d]*h1[d] + sum_{s->d} dinv[s]*h1[s]) + b1
__global__ __launch_bounds__(256) void agg1_kernel(const float* __restrict__ h1,
    const int* __restrict__ row, const int* __restrict__ srcs,
    const float* __restrict__ dinv, const float* __restrict__ b1,
    float* __restrict__ hidden) {
  int wave = (blockIdx.x * 256 + threadIdx.x) >> 6;
  int lane = threadIdx.x & 63;
  if (wave >= GN) return;
  int d = wave;
  float di = dinv[d];
  float2 acc = ((const float2*)(h1 + (size_t)d * 128))[lane];
  acc.x *= di; acc.y *= di;                       // self-loop: dinv[d]^2 after final *di
  int e0 = row[d], e1 = row[d + 1];
  int i = e0;
  for (; i + 4 <= e1; i += 4) {
    int s0 = srcs[i], s1 = srcs[i + 1], s2 = srcs[i + 2], s3 = srcs[i + 3];
    float w0 = dinv[s0], w1 = dinv[s1], w2 = dinv[s2], w3 = dinv[s3];
    float2 v0 = ((const float2*)(h1 + (size_t)s0 * 128))[lane];
    float2 v1 = ((const float2*)(h1 + (size_t)s1 * 128))[lane];
    float2 v2 = ((const float2*)(h1 + (size_t)s2 * 128))[lane];
    float2 v3 = ((const float2*)(h1 + (size_t)s3 * 128))[lane];
    acc.x += w0 * v0.x; acc.y += w0 * v0.y;
    acc.x += w1 * v1.x; acc.y += w1 * v1.y;
    acc.x += w2 * v2.x; acc.y += w2 * v2.y;
    acc.x += w3 * v3.x; acc.y += w3 * v3.y;
  }
  for (; i < e1; ++i) {
    int s = srcs[i];
    float w = dinv[s];
    float2 v = ((const float2*)(h1 + (size_t)s * 128))[lane];
    acc.x += w * v.x; acc.y += w * v.y;
  }
  float2 b = ((const float2*)b1)[lane];
  float2 o; o.x = acc.x * di + b.x; o.y = acc.y * di + b.y;
  ((float2*)(hidden + (size_t)d * 128))[lane] = o;
}

__global__ __launch_bounds__(256) void agg2_kernel(const float* __restrict__ h2,
    const int* __restrict__ row, const int* __restrict__ srcs,
    const float* __restrict__ dinv, const float* __restrict__ b2,
    float* __restrict__ out) {
  int wave = (blockIdx.x * 256 + threadIdx.x) >> 6;
  int lane = threadIdx.x & 63;
  if (wave >= GN) return;
  int d = wave;
  float di = dinv[d];
  float acc = h2[(size_t)d * 64 + lane] * di;
  int e0 = row[d], e1 = row[d + 1];
  int i = e0;
  for (; i + 4 <= e1; i += 4) {
    int s0 = srcs[i], s1 = srcs[i + 1], s2 = srcs[i + 2], s3 = srcs[i + 3];
    float w0 = dinv[s0], w1 = dinv[s1], w2 = dinv[s2], w3 = dinv[s3];
    float v0 = h2[(size_t)s0 * 64 + lane];
    float v1 = h2[(size_t)s1 * 64 + lane];
    float v2 = h2[(size_t)s2 * 64 + lane];
    float v3 = h2[(size_t)s3 * 64 + lane];
    acc += w0 * v0 + w1 * v1 + w2 * v2 + w3 * v3;
  }
  for (; i < e1; ++i) {
    int s = srcs[i];
    acc += dinv[s] * h2[(size_t)s * 64 + lane];
  }
  out[(size_t)d * 64 + lane] = acc * di + b2[lane];
}

__global__ __launch_bounds__(256) void bn_stats_kernel(const float* __restrict__ h,
    float* __restrict__ sum, float* __restrict__ sumsq) {
  int gt = blockIdx.x * 256 + threadIdx.x;   // 65536 threads = 512 row streams x 128 cols
  int c = gt & 127;
  int r = gt >> 7;
  float s = 0.f, ss = 0.f;
  for (; r < GN; r += 512) { float v = h[(size_t)r * 128 + c]; s += v; ss += v * v; }
  atomicAdd(&sum[c], s);
  atomicAdd(&sumsq[c], ss);
}

__global__ __launch_bounds__(128) void bn_final_kernel(const float* __restrict__ sum,
    const float* __restrict__ sumsq, const float* __restrict__ gamma,
    const float* __restrict__ beta, float* __restrict__ scale, float* __restrict__ shift) {
  int c = threadIdx.x;
  float mean = sum[c] * (1.0f / GN);
  float var = sumsq[c] * (1.0f / GN) - mean * mean;
  float istd = rsqrtf(var + 1e-5f);
  float g = gamma[c] * istd;
  scale[c] = g;
  shift[c] = beta[c] - mean * g;
}

extern "C" void kernel_launch(void* const* d_in, const int* in_sizes, int n_in,
                              void* d_out, int out_size, void* d_ws, size_t ws_size,
                              hipStream_t stream) {
  const float* x     = (const float*)d_in[0];
  const int*   e1    = (const int*)d_in[1];
  const int*   e2    = (const int*)d_in[2];
  const float* W1    = (const float*)d_in[3];
  const float* b1    = (const float*)d_in[4];
  const float* gamma = (const float*)d_in[5];
  const float* beta  = (const float*)d_in[6];
  const float* W2    = (const float*)d_in[7];
  const float* b2    = (const float*)d_in[8];

  float* out    = (float*)d_out;               // [N,64]
  float* hidden = out + (size_t)GN * OUTC;     // [N,128] second tuple element

  float* ws    = (float*)d_ws;
  float* h1    = ws + OFF_H1;
  float* h2    = ws + OFF_H2;
  float* dinv1 = ws + OFF_DINV1;
  float* dinv2 = ws + OFF_DINV2;
  int*   row1  = (int*)(ws + OFF_ROW1);
  int*   row2  = (int*)(ws + OFF_ROW2);
  int*   cur1  = (int*)(ws + OFF_CUR1);
  int*   cur2  = (int*)(ws + OFF_CUR2);
  int*   cnt1  = (int*)(ws + OFF_CNT1);
  int*   cnt2  = (int*)(ws + OFF_CNT2);
  float* bnbuf = ws + OFF_BN;
  int*   src1  = (int*)(ws + OFF_SRC1);
  int*   src2  = (int*)(ws + OFF_SRC2);
  int*   bsum  = (int*)(ws + OFF_BSUM);
  int*   bofs  = (int*)(ws + OFF_BOFS);
  int*   bcur1 = (int*)(ws + OFF_BCUR1);
  int*   bcur2 = (int*)(ws + OFF_BCUR2);
  // bucket buffers alias h2: consumed (bucket_fill) before gemm2 produces h2
  int*   pb1   = (int*)h2;
  int*   pb2   = pb1 + GE;

  // zero cnt1, cnt2, bn sums (contiguous region)
  hipMemsetAsync(ws + OFF_CNT1, 0, (size_t)(2 * GN + 512) * sizeof(float), stream);

  count_kernel<<<(GE + 255) / 256, 256, 0, stream>>>(e1, e2, cnt1, cnt2);
  scanA_kernel<<<2 * NB, 256, 0, stream>>>(cnt1, cnt2, bsum);
  scanB_kernel<<<1, 256, 0, stream>>>(bsum, bofs, row1, row2);
  scanC_kernel<<<2 * NB, 256, 0, stream>>>(cnt1, cnt2, bofs,
                                           row1, cur1, dinv1, row2, cur2, dinv2,
                                           bcur1, bcur2);
  bucket_scatter_kernel<<<dim3(1024, 2), 256, 0, stream>>>(e1, e2, bcur1, bcur2, pb1, pb2);
  bucket_fill_kernel<<<dim3((NBUCK * 64 + 255) / 256, 2), 256, 0, stream>>>(
      pb1, pb2, row1, row2, cur1, cur2, src1, src2);

  gemm1_kernel<<<dim3((GN + 31) / 32, 2), 256, 0, stream>>>(x, W1, h1);
  agg1_kernel<<<(GN * 64 + 255) / 256, 256, 0, stream>>>(h1, row1, src1, dinv1, b1, hidden);

  bn_stats_kernel<<<256, 256, 0, stream>>>(hidden, bnbuf, bnbuf + 128);
  bn_final_kernel<<<1, 128, 0, stream>>>(bnbuf, bnbuf + 128, gamma, beta,
                                         bnbuf + 256, bnbuf + 384);

  gemm2_kernel<<<dim3((GN + 31) / 32, 1), 256, 0, stream>>>(hidden, W2,
                                                            bnbuf + 256, bnbuf + 384, h2);
  agg2_kernel<<<(GN * 64 + 255) / 256, 256, 0, stream>>>(h2, row2, src2, dinv2, b2, out);
}

// Round 7
// 326.353 us; speedup vs baseline: 1.9725x; 1.9725x over previous
//
#include <hip/hip_runtime.h>

#define GN 50000      // nodes
#define GE 800000     // edges per graph
#define HID 128
#define OUTC 64
#define NBK 196       // buckets of 256 nodes: ceil(50000/256)
#define NW  196       // WGs per graph in pass 1: ceil(800000/4096)
#define EPW 4096      // edges per WG
#define PCAP 5888     // p2sort stage capacity (bucket mean 4082, sd ~64 -> +28 sd)

// workspace layout (float element offsets)
#define OFF_H1    0            // 6,400,000 f  (x@W1)
#define OFF_H2    6400000      // 3,200,000 f  (h2) -- aliased: packed pair buffers
#define OFF_DINV1 9600000      // 50,000
#define OFF_DINV2 9650000      // 50,000
#define OFF_ROW1  9700000      // 50,001 int
#define OFF_ROW2  9750004      // 50,001 int
#define OFF_HIST  9800008      // 2*NW*NBK = 76,832 int
#define OFF_TOT   9876840      // 2*NBK int
#define OFF_BBASE 9877232      // 2*(NBK+1) int
#define OFF_BN    9878000      // 512 f: sum@0 sumsq@128 scale@256 shift@384  -- memset

// pass 1a: per-WG histogram over dst buckets (LDS only, no global atomics)
__global__ __launch_bounds__(256) void p1hist_kernel(const int* __restrict__ e1,
    const int* __restrict__ e2, int* __restrict__ hist) {
  __shared__ int h[NBK];
  int g = blockIdx.y, w = blockIdx.x;
  const int* dst = (g ? e2 : e1) + GE;
  for (int i = threadIdx.x; i < NBK; i += 256) h[i] = 0;
  __syncthreads();
  int i0 = w * EPW, iend = i0 + EPW; if (iend > GE) iend = GE;
  for (int i = i0 + threadIdx.x; i < iend; i += 256)
    atomicAdd(&h[dst[i] >> 8], 1);
  __syncthreads();
  int* out = hist + ((size_t)g * NW + w) * NBK;
  for (int i = threadIdx.x; i < NBK; i += 256) out[i] = h[i];
}

// pass 1b: per-bucket exclusive scan over WGs (in place); bucket totals out
__global__ __launch_bounds__(256) void histscanA_kernel(int* __restrict__ hist,
    int* __restrict__ tot) {
  __shared__ int lds[256];
  int b = blockIdx.x, g = blockIdx.y, t = threadIdx.x;
  int* col = hist + (size_t)g * NW * NBK + b;   // stride NBK over w
  int v = (t < NW) ? col[(size_t)t * NBK] : 0;
  lds[t] = v;
  __syncthreads();
  for (int off = 1; off < 256; off <<= 1) {
    int u = (t >= off) ? lds[t - off] : 0;
    __syncthreads();
    lds[t] += u;
    __syncthreads();
  }
  if (t < NW) col[(size_t)t * NBK] = lds[t] - v;   // exclusive
  if (t == NW - 1) tot[g * NBK + b] = lds[t];
}

// pass 1c: 1 block — exclusive scan bucket totals -> bucket bases (NBK+1 entries)
__global__ __launch_bounds__(256) void histscanB_kernel(const int* __restrict__ tot,
    int* __restrict__ bbase) {
  __shared__ int lds[256];
  int t = threadIdx.x;
  for (int g = 0; g < 2; ++g) {
    int v = (t < NBK) ? tot[g * NBK + t] : 0;
    int orig = v;
    lds[t] = v;
    __syncthreads();
    for (int off = 1; off < 256; off <<= 1) {
      int u = (t >= off) ? lds[t - off] : 0;
      __syncthreads();
      lds[t] += u;
      __syncthreads();
    }
    if (t < NBK) bbase[g * (NBK + 1) + t] = lds[t] - orig;
    if (t == NBK - 1) bbase[g * (NBK + 1) + NBK] = lds[t];
    __syncthreads();
  }
}

// pass 1d: re-read edges; rank via LDS counters; write packed (src | localdst<<16)
// in ~21-entry contiguous runs per (WG,bucket)
__global__ __launch_bounds__(256) void p1scat_kernel(const int* __restrict__ e1,
    const int* __restrict__ e2, const int* __restrict__ hist,
    const int* __restrict__ bbase, int* __restrict__ pb1, int* __restrict__ pb2) {
  __shared__ int off[NBK];
  int g = blockIdx.y, w = blockIdx.x;
  const int* e = g ? e2 : e1;
  int* pb = g ? pb2 : pb1;
  const int* hrow = hist + ((size_t)g * NW + w) * NBK;
  const int* bb = bbase + g * (NBK + 1);
  for (int i = threadIdx.x; i < NBK; i += 256) off[i] = bb[i] + hrow[i];
  __syncthreads();
  int i0 = w * EPW, iend = i0 + EPW; if (iend > GE) iend = GE;
  for (int i = i0 + threadIdx.x; i < iend; i += 256) {
    int d = e[GE + i], s = e[i];
    int p = atomicAdd(&off[d >> 8], 1);
    pb[p] = s | ((d & 255) << 16);   // s < 50000 < 2^16; packed < 2^24
  }
}

// pass 2: one WG per bucket — LDS counting sort by node; coalesced writes of
// src span + row + dinv. Also derives degrees (so no count/scan kernels needed).
__global__ __launch_bounds__(256) void p2sort_kernel(const int* __restrict__ pb1,
    const int* __restrict__ pb2, const int* __restrict__ bbase,
    int* __restrict__ row1, int* __restrict__ row2,
    float* __restrict__ dinv1, float* __restrict__ dinv2,
    int* __restrict__ src1, int* __restrict__ src2) {
  __shared__ int stage[PCAP];
  __shared__ int lcnt[256], lc2[256], arr[256];
  __shared__ int lrow[257];
  int g = blockIdx.y, b = blockIdx.x, t = threadIdx.x;
  const int* pb = g ? pb2 : pb1;
  const int* bb = bbase + g * (NBK + 1);
  int* row = g ? row2 : row1;
  float* dinv = g ? dinv2 : dinv1;
  int* src = g ? src2 : src1;
  int lo = b << 8, hi = lo + 256; if (hi > GN) hi = GN;
  int nn = hi - lo;
  int base = bb[b], end = bb[b + 1], L = end - base;
  lcnt[t] = 0; lc2[t] = 0;
  __syncthreads();
  // pass A: per-node counts
  for (int i = base + t; i < end; i += 256)
    atomicAdd(&lcnt[((unsigned)pb[i]) >> 16], 1);
  __syncthreads();
  // exclusive scan lcnt -> lrow
  int v = lcnt[t];
  arr[t] = v;
  __syncthreads();
  for (int off = 1; off < 256; off <<= 1) {
    int u = (t >= off) ? arr[t - off] : 0;
    __syncthreads();
    arr[t] += u;
    __syncthreads();
  }
  lrow[t] = arr[t] - v;
  if (t == 255) lrow[256] = arr[255];
  __syncthreads();
  // row/dinv for this bucket's nodes (coalesced)
  if (t < nn) {
    row[lo + t] = base + lrow[t];
    dinv[lo + t] = rsqrtf(1.0f + (float)lcnt[t]);
  }
  if (b == NBK - 1 && t == 0) row[GN] = end;
  // pass B: rank + stage, then contiguous write-out
  if (L <= PCAP) {
    for (int i = base + t; i < end; i += 256) {
      unsigned p = (unsigned)pb[i];
      int ld = p >> 16;
      int rk = atomicAdd(&lc2[ld], 1);
      stage[lrow[ld] + rk] = (int)(p & 0xFFFFu);
    }
    __syncthreads();
    for (int i = t; i < L; i += 256) src[base + i] = stage[i];
  } else {   // overflow fallback (statistically unreachable): direct scatter
    for (int i = base + t; i < end; i += 256) {
      unsigned p = (unsigned)pb[i];
      int ld = p >> 16;
      int rk = atomicAdd(&lc2[ld], 1);
      src[base + lrow[ld] + rk] = (int)(p & 0xFFFFu);
    }
  }
}

// C[M,128] = A[M,128] @ B[128,128]; block tile 32 rows x 64 cols (blockIdx.y selects col half)
__global__ __launch_bounds__(256) void gemm1_kernel(const float* __restrict__ A,
    const float* __restrict__ B, float* __restrict__ C) {
  __shared__ __align__(16) float wlds[128 * 64];
  __shared__ __align__(16) float alds[32 * 128];
  int t = threadIdx.x;
  int row0 = blockIdx.x * 32;
  int cb = blockIdx.y * 64;
  for (int i = t; i < 128 * 16; i += 256) {        // W tile: 128 rows x 16 float4
    int k = i >> 4, c4 = i & 15;
    ((float4*)wlds)[i] = ((const float4*)B)[k * 32 + (cb >> 2) + c4];
  }
  for (int i = t; i < 1024; i += 256) {            // A tile: 32 rows x 32 float4
    int r = i >> 5, c4 = i & 31;
    int gr = row0 + r;
    ((float4*)alds)[i] = (gr < GN) ? ((const float4*)A)[(size_t)gr * 32 + c4]
                                   : make_float4(0.f, 0.f, 0.f, 0.f);
  }
  __syncthreads();
  int j0 = (t & 15) * 4;
  int r0 = (t >> 4) * 2;
  float4 acc0 = {0, 0, 0, 0}, acc1 = {0, 0, 0, 0};
  #pragma unroll 8
  for (int k = 0; k < 128; ++k) {
    float4 w = *(const float4*)&wlds[k * 64 + j0];
    float a0 = alds[r0 * 128 + k];
    float a1 = alds[(r0 + 1) * 128 + k];
    acc0.x += a0 * w.x; acc0.y += a0 * w.y; acc0.z += a0 * w.z; acc0.w += a0 * w.w;
    acc1.x += a1 * w.x; acc1.y += a1 * w.y; acc1.z += a1 * w.z; acc1.w += a1 * w.w;
  }
  int gr0 = row0 + r0;
  if (gr0 < GN)     *(float4*)&C[(size_t)gr0 * 128 + cb + j0] = acc0;
  if (gr0 + 1 < GN) *(float4*)&C[(size_t)(gr0 + 1) * 128 + cb + j0] = acc1;
}

// C[M,64] = relu(bn(A[M,128])) @ B[128,64]
__global__ __launch_bounds__(256) void gemm2_kernel(const float* __restrict__ A,
    const float* __restrict__ B, const float* __restrict__ scale,
    const float* __restrict__ shift, float* __restrict__ C) {
  __shared__ __align__(16) float wlds[128 * 64];
  __shared__ __align__(16) float alds[32 * 128];
  __shared__ float sc[128], sh[128];
  int t = threadIdx.x;
  if (t < 128) { sc[t] = scale[t]; sh[t] = shift[t]; }
  int row0 = blockIdx.x * 32;
  for (int i = t; i < 128 * 16; i += 256)
    ((float4*)wlds)[i] = ((const float4*)B)[i];
  __syncthreads();   // sc/sh ready before prologue
  for (int i = t; i < 1024; i += 256) {
    int r = i >> 5, c4 = i & 31;
    int gr = row0 + r;
    float4 v = (gr < GN) ? ((const float4*)A)[(size_t)gr * 32 + c4]
                         : make_float4(0.f, 0.f, 0.f, 0.f);
    int c = c4 * 4;
    v.x = fmaxf(fmaf(v.x, sc[c],     sh[c]),     0.f);
    v.y = fmaxf(fmaf(v.y, sc[c + 1], sh[c + 1]), 0.f);
    v.z = fmaxf(fmaf(v.z, sc[c + 2], sh[c + 2]), 0.f);
    v.w = fmaxf(fmaf(v.w, sc[c + 3], sh[c + 3]), 0.f);
    ((float4*)alds)[i] = v;
  }
  __syncthreads();
  int j0 = (t & 15) * 4;
  int r0 = (t >> 4) * 2;
  float4 acc0 = {0, 0, 0, 0}, acc1 = {0, 0, 0, 0};
  #pragma unroll 8
  for (int k = 0; k < 128; ++k) {
    float4 w = *(const float4*)&wlds[k * 64 + j0];
    float a0 = alds[r0 * 128 + k];
    float a1 = alds[(r0 + 1) * 128 + k];
    acc0.x += a0 * w.x; acc0.y += a0 * w.y; acc0.z += a0 * w.z; acc0.w += a0 * w.w;
    acc1.x += a1 * w.x; acc1.y += a1 * w.y; acc1.z += a1 * w.z; acc1.w += a1 * w.w;
  }
  int gr0 = row0 + r0;
  if (gr0 < GN)     *(float4*)&C[(size_t)gr0 * 64 + j0] = acc0;
  if (gr0 + 1 < GN) *(float4*)&C[(size_t)(gr0 + 1) * 64 + j0] = acc1;
}

// wave-per-node gather, 4x unrolled:
// hidden[d] = dinv[d]*(dinv[d]*h1[d] + sum_{s->d} dinv[s]*h1[s]) + b1
__global__ __launch_bounds__(256) void agg1_kernel(const float* __restrict__ h1,
    const int* __restrict__ row, const int* __restrict__ srcs,
    const float* __restrict__ dinv, const float* __restrict__ b1,
    float* __restrict__ hidden) {
  int wave = (blockIdx.x * 256 + threadIdx.x) >> 6;
  int lane = threadIdx.x & 63;
  if (wave >= GN) return;
  int d = wave;
  float di = dinv[d];
  float2 acc = ((const float2*)(h1 + (size_t)d * 128))[lane];
  acc.x *= di; acc.y *= di;                       // self-loop: dinv[d]^2 after final *di
  int e0 = row[d], e1 = row[d + 1];
  int i = e0;
  for (; i + 4 <= e1; i += 4) {
    int s0 = srcs[i], s1 = srcs[i + 1], s2 = srcs[i + 2], s3 = srcs[i + 3];
    float w0 = dinv[s0], w1 = dinv[s1], w2 = dinv[s2], w3 = dinv[s3];
    float2 v0 = ((const float2*)(h1 + (size_t)s0 * 128))[lane];
    float2 v1 = ((const float2*)(h1 + (size_t)s1 * 128))[lane];
    float2 v2 = ((const float2*)(h1 + (size_t)s2 * 128))[lane];
    float2 v3 = ((const float2*)(h1 + (size_t)s3 * 128))[lane];
    acc.x += w0 * v0.x; acc.y += w0 * v0.y;
    acc.x += w1 * v1.x; acc.y += w1 * v1.y;
    acc.x += w2 * v2.x; acc.y += w2 * v2.y;
    acc.x += w3 * v3.x; acc.y += w3 * v3.y;
  }
  for (; i < e1; ++i) {
    int s = srcs[i];
    float w = dinv[s];
    float2 v = ((const float2*)(h1 + (size_t)s * 128))[lane];
    acc.x += w * v.x; acc.y += w * v.y;
  }
  float2 b = ((const float2*)b1)[lane];
  float2 o; o.x = acc.x * di + b.x; o.y = acc.y * di + b.y;
  ((float2*)(hidden + (size_t)d * 128))[lane] = o;
}

__global__ __launch_bounds__(256) void agg2_kernel(const float* __restrict__ h2,
    const int* __restrict__ row, const int* __restrict__ srcs,
    const float* __restrict__ dinv, const float* __restrict__ b2,
    float* __restrict__ out) {
  int wave = (blockIdx.x * 256 + threadIdx.x) >> 6;
  int lane = threadIdx.x & 63;
  if (wave >= GN) return;
  int d = wave;
  float di = dinv[d];
  float acc = h2[(size_t)d * 64 + lane] * di;
  int e0 = row[d], e1 = row[d + 1];
  int i = e0;
  for (; i + 4 <= e1; i += 4) {
    int s0 = srcs[i], s1 = srcs[i + 1], s2 = srcs[i + 2], s3 = srcs[i + 3];
    float w0 = dinv[s0], w1 = dinv[s1], w2 = dinv[s2], w3 = dinv[s3];
    float v0 = h2[(size_t)s0 * 64 + lane];
    float v1 = h2[(size_t)s1 * 64 + lane];
    float v2 = h2[(size_t)s2 * 64 + lane];
    float v3 = h2[(size_t)s3 * 64 + lane];
    acc += w0 * v0 + w1 * v1 + w2 * v2 + w3 * v3;
  }
  for (; i < e1; ++i) {
    int s = srcs[i];
    acc += dinv[s] * h2[(size_t)s * 64 + lane];
  }
  out[(size_t)d * 64 + lane] = acc * di + b2[lane];
}

__global__ __launch_bounds__(256) void bn_stats_kernel(const float* __restrict__ h,
    float* __restrict__ sum, float* __restrict__ sumsq) {
  int gt = blockIdx.x * 256 + threadIdx.x;   // 65536 threads = 512 row streams x 128 cols
  int c = gt & 127;
  int r = gt >> 7;
  float s = 0.f, ss = 0.f;
  for (; r < GN; r += 512) { float v = h[(size_t)r * 128 + c]; s += v; ss += v * v; }
  atomicAdd(&sum[c], s);
  atomicAdd(&sumsq[c], ss);
}

__global__ __launch_bounds__(128) void bn_final_kernel(const float* __restrict__ sum,
    const float* __restrict__ sumsq, const float* __restrict__ gamma,
    const float* __restrict__ beta, float* __restrict__ scale, float* __restrict__ shift) {
  int c = threadIdx.x;
  float mean = sum[c] * (1.0f / GN);
  float var = sumsq[c] * (1.0f / GN) - mean * mean;
  float istd = rsqrtf(var + 1e-5f);
  float g = gamma[c] * istd;
  scale[c] = g;
  shift[c] = beta[c] - mean * g;
}

extern "C" void kernel_launch(void* const* d_in, const int* in_sizes, int n_in,
                              void* d_out, int out_size, void* d_ws, size_t ws_size,
                              hipStream_t stream) {
  const float* x     = (const float*)d_in[0];
  const int*   e1    = (const int*)d_in[1];
  const int*   e2    = (const int*)d_in[2];
  const float* W1    = (const float*)d_in[3];
  const float* b1    = (const float*)d_in[4];
  const float* gamma = (const float*)d_in[5];
  const float* beta  = (const float*)d_in[6];
  const float* W2    = (const float*)d_in[7];
  const float* b2    = (const float*)d_in[8];

  float* out    = (float*)d_out;               // [N,64]
  float* hidden = out + (size_t)GN * OUTC;     // [N,128] second tuple element

  float* ws    = (float*)d_ws;
  float* h1    = ws + OFF_H1;
  float* h2    = ws + OFF_H2;
  float* dinv1 = ws + OFF_DINV1;
  float* dinv2 = ws + OFF_DINV2;
  int*   row1  = (int*)(ws + OFF_ROW1);
  int*   row2  = (int*)(ws + OFF_ROW2);
  int*   hist  = (int*)(ws + OFF_HIST);
  int*   tot   = (int*)(ws + OFF_TOT);
  int*   bbase = (int*)(ws + OFF_BBASE);
  float* bnbuf = ws + OFF_BN;
  // src arrays: place in dedicated region after BN (well within ws)
  int*   src1  = (int*)(ws + 9900000);
  int*   src2  = src1 + GE;
  // packed pair buffers alias h2: consumed (p2sort) before gemm2 produces h2
  int*   pb1   = (int*)h2;
  int*   pb2   = pb1 + GE;

  // zero BN sums only
  hipMemsetAsync(ws + OFF_BN, 0, 512 * sizeof(float), stream);

  p1hist_kernel<<<dim3(NW, 2), 256, 0, stream>>>(e1, e2, hist);
  histscanA_kernel<<<dim3(NBK, 2), 256, 0, stream>>>(hist, tot);
  histscanB_kernel<<<1, 256, 0, stream>>>(tot, bbase);
  p1scat_kernel<<<dim3(NW, 2), 256, 0, stream>>>(e1, e2, hist, bbase, pb1, pb2);
  p2sort_kernel<<<dim3(NBK, 2), 256, 0, stream>>>(pb1, pb2, bbase,
                                                  row1, row2, dinv1, dinv2, src1, src2);

  gemm1_kernel<<<dim3((GN + 31) / 32, 2), 256, 0, stream>>>(x, W1, h1);
  agg1_kernel<<<(GN * 64 + 255) / 256, 256, 0, stream>>>(h1, row1, src1, dinv1, b1, hidden);

  bn_stats_kernel<<<256, 256, 0, stream>>>(hidden, bnbuf, bnbuf + 128);
  bn_final_kernel<<<1, 128, 0, stream>>>(bnbuf, bnbuf + 128, gamma, beta,
                                         bnbuf + 256, bnbuf + 384);

  gemm2_kernel<<<dim3((GN + 31) / 32, 1), 256, 0, stream>>>(hidden, W2,
                                                            bnbuf + 256, bnbuf + 384, h2);
  agg2_kernel<<<(GN * 64 + 255) / 256, 256, 0, stream>>>(h2, row2, src2, dinv2, b2, out);
}

// Round 9
// 293.277 us; speedup vs baseline: 2.1950x; 1.1128x over previous
//
#include <hip/hip_runtime.h>

#define GN 50000      // nodes
#define GE 800000     // edges per graph
#define HID 128
#define OUTC 64
#define NBK 196       // buckets of 256 nodes: ceil(50000/256)
#define NW  196       // WGs per graph in pass 1: ceil(800000/4096)
#define EPW 4096      // edges per WG
#define PCAP 5888     // p2sort stage capacity (bucket mean 4082, sd ~64)
#define A1B 2048      // agg1 blocks (grid-stride, 8192 waves)

// workspace layout (float element offsets)
#define OFF_H1    0            // h1 bf16: GN*128 ushort = 3.2M floats
#define OFF_H2    3200000      // h2 bf16: GN*64 ushort = 1.6M floats -- aliased: pb1/pb2
#define OFF_DINV1 4800000      // 50,000
#define OFF_DINV2 4850000      // 50,000
#define OFF_ROW1  4900000      // 50,001 int
#define OFF_ROW2  4950004      // 50,001 int
#define OFF_HIST  5000008      // 2*NW*NBK = 76,832 int
#define OFF_TOT   5076840      // 2*NBK int
#define OFF_BBASE 5077232      // 2*(NBK+1) int
#define OFF_BN    5077632      // 512 f: scale@0 shift@128
#define OFF_PART  5078144      // A1B*256 f = 524,288
#define OFF_PARTA 5602432      // 16*256 f
#define OFF_SRC1  5606528      // 800,000 int
#define OFF_SRC2  6406528      // 800,000 int

__device__ inline unsigned bf16rne(float f) {
  unsigned u = __float_as_uint(f);
  return (u + 0x7FFFu + ((u >> 16) & 1u)) >> 16;
}
__device__ inline unsigned pack2(float a, float b) {
  return bf16rne(a) | (bf16rne(b) << 16);
}
__device__ inline float bflo(unsigned w) { return __uint_as_float(w << 16); }
__device__ inline float bfhi(unsigned w) { return __uint_as_float(w & 0xFFFF0000u); }

// ---------------- CSR build: LDS counting sort (R7, unchanged) ----------------
__global__ __launch_bounds__(256) void p1hist_kernel(const int* __restrict__ e1,
    const int* __restrict__ e2, int* __restrict__ hist) {
  __shared__ int h[NBK];
  int g = blockIdx.y, w = blockIdx.x;
  const int* dst = (g ? e2 : e1) + GE;
  for (int i = threadIdx.x; i < NBK; i += 256) h[i] = 0;
  __syncthreads();
  int i0 = w * EPW, iend = i0 + EPW; if (iend > GE) iend = GE;
  for (int i = i0 + threadIdx.x; i < iend; i += 256)
    atomicAdd(&h[dst[i] >> 8], 1);
  __syncthreads();
  int* out = hist + ((size_t)g * NW + w) * NBK;
  for (int i = threadIdx.x; i < NBK; i += 256) out[i] = h[i];
}

__global__ __launch_bounds__(256) void histscanA_kernel(int* __restrict__ hist,
    int* __restrict__ tot) {
  __shared__ int lds[256];
  int b = blockIdx.x, g = blockIdx.y, t = threadIdx.x;
  int* col = hist + (size_t)g * NW * NBK + b;
  int v = (t < NW) ? col[(size_t)t * NBK] : 0;
  lds[t] = v;
  __syncthreads();
  for (int off = 1; off < 256; off <<= 1) {
    int u = (t >= off) ? lds[t - off] : 0;
    __syncthreads();
    lds[t] += u;
    __syncthreads();
  }
  if (t < NW) col[(size_t)t * NBK] = lds[t] - v;
  if (t == NW - 1) tot[g * NBK + b] = lds[t];
}

__global__ __launch_bounds__(256) void histscanB_kernel(const int* __restrict__ tot,
    int* __restrict__ bbase) {
  __shared__ int lds[256];
  int t = threadIdx.x;
  for (int g = 0; g < 2; ++g) {
    int v = (t < NBK) ? tot[g * NBK + t] : 0;
    int orig = v;
    lds[t] = v;
    __syncthreads();
    for (int off = 1; off < 256; off <<= 1) {
      int u = (t >= off) ? lds[t - off] : 0;
      __syncthreads();
      lds[t] += u;
      __syncthreads();
    }
    if (t < NBK) bbase[g * (NBK + 1) + t] = lds[t] - orig;
    if (t == NBK - 1) bbase[g * (NBK + 1) + NBK] = lds[t];
    __syncthreads();
  }
}

__global__ __launch_bounds__(256) void p1scat_kernel(const int* __restrict__ e1,
    const int* __restrict__ e2, const int* __restrict__ hist,
    const int* __restrict__ bbase, int* __restrict__ pb1, int* __restrict__ pb2) {
  __shared__ int off[NBK];
  int g = blockIdx.y, w = blockIdx.x;
  const int* e = g ? e2 : e1;
  int* pb = g ? pb2 : pb1;
  const int* hrow = hist + ((size_t)g * NW + w) * NBK;
  const int* bb = bbase + g * (NBK + 1);
  for (int i = threadIdx.x; i < NBK; i += 256) off[i] = bb[i] + hrow[i];
  __syncthreads();
  int i0 = w * EPW, iend = i0 + EPW; if (iend > GE) iend = GE;
  for (int i = i0 + threadIdx.x; i < iend; i += 256) {
    int d = e[GE + i], s = e[i];
    int p = atomicAdd(&off[d >> 8], 1);
    pb[p] = s | ((d & 255) << 16);
  }
}

__global__ __launch_bounds__(256) void p2sort_kernel(const int* __restrict__ pb1,
    const int* __restrict__ pb2, const int* __restrict__ bbase,
    int* __restrict__ row1, int* __restrict__ row2,
    float* __restrict__ dinv1, float* __restrict__ dinv2,
    int* __restrict__ src1, int* __restrict__ src2) {
  __shared__ int stage[PCAP];
  __shared__ int lcnt[256], lc2[256], arr[256];
  __shared__ int lrow[257];
  int g = blockIdx.y, b = blockIdx.x, t = threadIdx.x;
  const int* pb = g ? pb2 : pb1;
  const int* bb = bbase + g * (NBK + 1);
  int* row = g ? row2 : row1;
  float* dinv = g ? dinv2 : dinv1;
  int* src = g ? src2 : src1;
  int lo = b << 8, hi = lo + 256; if (hi > GN) hi = GN;
  int nn = hi - lo;
  int base = bb[b], end = bb[b + 1], L = end - base;
  lcnt[t] = 0; lc2[t] = 0;
  __syncthreads();
  for (int i = base + t; i < end; i += 256)
    atomicAdd(&lcnt[((unsigned)pb[i]) >> 16], 1);
  __syncthreads();
  int v = lcnt[t];
  arr[t] = v;
  __syncthreads();
  for (int off = 1; off < 256; off <<= 1) {
    int u = (t >= off) ? arr[t - off] : 0;
    __syncthreads();
    arr[t] += u;
    __syncthreads();
  }
  lrow[t] = arr[t] - v;
  if (t == 255) lrow[256] = arr[255];
  __syncthreads();
  if (t < nn) {
    row[lo + t] = base + lrow[t];
    dinv[lo + t] = rsqrtf(1.0f + (float)lcnt[t]);
  }
  if (b == NBK - 1 && t == 0) row[GN] = end;
  if (L <= PCAP) {
    for (int i = base + t; i < end; i += 256) {
      unsigned p = (unsigned)pb[i];
      int ld = p >> 16;
      int rk = atomicAdd(&lc2[ld], 1);
      stage[lrow[ld] + rk] = (int)(p & 0xFFFFu);
    }
    __syncthreads();
    for (int i = t; i < L; i += 256) src[base + i] = stage[i];
  } else {
    for (int i = base + t; i < end; i += 256) {
      unsigned p = (unsigned)pb[i];
      int ld = p >> 16;
      int rk = atomicAdd(&lc2[ld], 1);
      src[base + lrow[ld] + rk] = (int)(p & 0xFFFFu);
    }
  }
}

// ---------------- GEMMs (bf16 packed output) ----------------
// h1b[M,128](bf16) = A[M,128] @ B[128,128]
__global__ __launch_bounds__(256) void gemm1_kernel(const float* __restrict__ A,
    const float* __restrict__ B, unsigned* __restrict__ h1b) {
  __shared__ __align__(16) float wlds[128 * 64];
  __shared__ __align__(16) float alds[32 * 128];
  int t = threadIdx.x;
  int row0 = blockIdx.x * 32;
  int cb = blockIdx.y * 64;
  for (int i = t; i < 128 * 16; i += 256) {
    int k = i >> 4, c4 = i & 15;
    ((float4*)wlds)[i] = ((const float4*)B)[k * 32 + (cb >> 2) + c4];
  }
  for (int i = t; i < 1024; i += 256) {
    int r = i >> 5, c4 = i & 31;
    int gr = row0 + r;
    ((float4*)alds)[i] = (gr < GN) ? ((const float4*)A)[(size_t)gr * 32 + c4]
                                   : make_float4(0.f, 0.f, 0.f, 0.f);
  }
  __syncthreads();
  int j0 = (t & 15) * 4;
  int r0 = (t >> 4) * 2;
  float4 acc0 = {0, 0, 0, 0}, acc1 = {0, 0, 0, 0};
  #pragma unroll 8
  for (int k = 0; k < 128; ++k) {
    float4 w = *(const float4*)&wlds[k * 64 + j0];
    float a0 = alds[r0 * 128 + k];
    float a1 = alds[(r0 + 1) * 128 + k];
    acc0.x += a0 * w.x; acc0.y += a0 * w.y; acc0.z += a0 * w.z; acc0.w += a0 * w.w;
    acc1.x += a1 * w.x; acc1.y += a1 * w.y; acc1.z += a1 * w.z; acc1.w += a1 * w.w;
  }
  int gr0 = row0 + r0;
  if (gr0 < GN) {
    uint2 p = make_uint2(pack2(acc0.x, acc0.y), pack2(acc0.z, acc0.w));
    ((uint2*)h1b)[((size_t)gr0 * 128 + cb + j0) >> 2] = p;
  }
  if (gr0 + 1 < GN) {
    uint2 p = make_uint2(pack2(acc1.x, acc1.y), pack2(acc1.z, acc1.w));
    ((uint2*)h1b)[((size_t)(gr0 + 1) * 128 + cb + j0) >> 2] = p;
  }
}

// h2b[M,64](bf16) = relu(bn(hidden[M,128])) @ B[128,64]
__global__ __launch_bounds__(256) void gemm2_kernel(const float* __restrict__ A,
    const float* __restrict__ B, const float* __restrict__ scale,
    const float* __restrict__ shift, unsigned* __restrict__ h2b) {
  __shared__ __align__(16) float wlds[128 * 64];
  __shared__ __align__(16) float alds[32 * 128];
  __shared__ float sc[128], sh[128];
  int t = threadIdx.x;
  if (t < 128) { sc[t] = scale[t]; sh[t] = shift[t]; }
  int row0 = blockIdx.x * 32;
  for (int i = t; i < 128 * 16; i += 256)
    ((float4*)wlds)[i] = ((const float4*)B)[i];
  __syncthreads();
  for (int i = t; i < 1024; i += 256) {
    int r = i >> 5, c4 = i & 31;
    int gr = row0 + r;
    float4 v = (gr < GN) ? ((const float4*)A)[(size_t)gr * 32 + c4]
                         : make_float4(0.f, 0.f, 0.f, 0.f);
    int c = c4 * 4;
    v.x = fmaxf(fmaf(v.x, sc[c],     sh[c]),     0.f);
    v.y = fmaxf(fmaf(v.y, sc[c + 1], sh[c + 1]), 0.f);
    v.z = fmaxf(fmaf(v.z, sc[c + 2], sh[c + 2]), 0.f);
    v.w = fmaxf(fmaf(v.w, sc[c + 3], sh[c + 3]), 0.f);
    ((float4*)alds)[i] = v;
  }
  __syncthreads();
  int j0 = (t & 15) * 4;
  int r0 = (t >> 4) * 2;
  float4 acc0 = {0, 0, 0, 0}, acc1 = {0, 0, 0, 0};
  #pragma unroll 8
  for (int k = 0; k < 128; ++k) {
    float4 w = *(const float4*)&wlds[k * 64 + j0];
    float a0 = alds[r0 * 128 + k];
    float a1 = alds[(r0 + 1) * 128 + k];
    acc0.x += a0 * w.x; acc0.y += a0 * w.y; acc0.z += a0 * w.z; acc0.w += a0 * w.w;
    acc1.x += a1 * w.x; acc1.y += a1 * w.y; acc1.z += a1 * w.z; acc1.w += a1 * w.w;
  }
  int gr0 = row0 + r0;
  if (gr0 < GN) {
    uint2 p = make_uint2(pack2(acc0.x, acc0.y), pack2(acc0.z, acc0.w));
    ((uint2*)h2b)[((size_t)gr0 * 64 + j0) >> 2] = p;
  }
  if (gr0 + 1 < GN) {
    uint2 p = make_uint2(pack2(acc1.x, acc1.y), pack2(acc1.z, acc1.w));
    ((uint2*)h2b)[((size_t)(gr0 + 1) * 64 + j0) >> 2] = p;
  }
}

// ---------------- Aggregations ----------------
// agg1: grid-stride wave-per-node bf16 gather, 8x unrolled, fused BN partial sums.
// hidden[d] = dinv[d]*(dinv[d]*h1[d] + sum dinv[s]*h1[s]) + b1  (fp32 out)
__global__ __launch_bounds__(256) void agg1_kernel(const unsigned* __restrict__ h1b,
    const int* __restrict__ row, const int* __restrict__ srcs,
    const float* __restrict__ dinv, const float* __restrict__ b1,
    float* __restrict__ hidden, float* __restrict__ part) {
  __shared__ float ps[256];
  int t = threadIdx.x;
  int lane = t & 63;
  int wid = (blockIdx.x * 256 + t) >> 6;   // 0..A1B*4-1
  float2 b = ((const float2*)b1)[lane];
  float sx = 0.f, sy = 0.f, qx = 0.f, qy = 0.f;
  for (int d = wid; d < GN; d += A1B * 4) {
    float di = dinv[d];
    unsigned sw = h1b[(size_t)d * 64 + lane];
    float ax = di * bflo(sw), ay = di * bfhi(sw);
    int e0 = row[d], e1 = row[d + 1];
    int i = e0;
    for (; i + 8 <= e1; i += 8) {
      int s0 = srcs[i],     s1 = srcs[i + 1], s2 = srcs[i + 2], s3 = srcs[i + 3];
      int s4 = srcs[i + 4], s5 = srcs[i + 5], s6 = srcs[i + 6], s7 = srcs[i + 7];
      float w0 = dinv[s0], w1 = dinv[s1], w2 = dinv[s2], w3 = dinv[s3];
      float w4 = dinv[s4], w5 = dinv[s5], w6 = dinv[s6], w7 = dinv[s7];
      unsigned v0 = h1b[(size_t)s0 * 64 + lane], v1 = h1b[(size_t)s1 * 64 + lane];
      unsigned v2 = h1b[(size_t)s2 * 64 + lane], v3 = h1b[(size_t)s3 * 64 + lane];
      unsigned v4 = h1b[(size_t)s4 * 64 + lane], v5 = h1b[(size_t)s5 * 64 + lane];
      unsigned v6 = h1b[(size_t)s6 * 64 + lane], v7 = h1b[(size_t)s7 * 64 + lane];
      ax += w0 * bflo(v0); ay += w0 * bfhi(v0);
      ax += w1 * bflo(v1); ay += w1 * bfhi(v1);
      ax += w2 * bflo(v2); ay += w2 * bfhi(v2);
      ax += w3 * bflo(v3); ay += w3 * bfhi(v3);
      ax += w4 * bflo(v4); ay += w4 * bfhi(v4);
      ax += w5 * bflo(v5); ay += w5 * bfhi(v5);
      ax += w6 * bflo(v6); ay += w6 * bfhi(v6);
      ax += w7 * bflo(v7); ay += w7 * bfhi(v7);
    }
    for (; i < e1; ++i) {
      int s = srcs[i];
      float w = dinv[s];
      unsigned v = h1b[(size_t)s * 64 + lane];
      ax += w * bflo(v); ay += w * bfhi(v);
    }
    float ox = ax * di + b.x, oy = ay * di + b.y;
    float2 o; o.x = ox; o.y = oy;
    ((float2*)(hidden + (size_t)d * 128))[lane] = o;
    sx += ox; sy += oy; qx += ox * ox; qy += oy * oy;
  }
  // block reduce: col 2*lane gets sx, col 2*lane+1 gets sy (4 waves/block)
  float* pout = part + (size_t)blockIdx.x * 256;
  ps[t] = sx; __syncthreads();
  if (t < 64) pout[2 * t] = ps[t] + ps[t + 64] + ps[t + 128] + ps[t + 192];
  __syncthreads();
  ps[t] = sy; __syncthreads();
  if (t < 64) pout[2 * t + 1] = ps[t] + ps[t + 64] + ps[t + 128] + ps[t + 192];
  __syncthreads();
  ps[t] = qx; __syncthreads();
  if (t < 64) pout[128 + 2 * t] = ps[t] + ps[t + 64] + ps[t + 128] + ps[t + 192];
  __syncthreads();
  ps[t] = qy; __syncthreads();
  if (t < 64) pout[128 + 2 * t + 1] = ps[t] + ps[t + 64] + ps[t + 128] + ps[t + 192];
}

// stage A of BN reduce: 16 blocks x 128 rows of partials (coalesced)
__global__ __launch_bounds__(256) void bn_reduceA_kernel(const float* __restrict__ part,
    float* __restrict__ partA) {
  int r = blockIdx.x, t = threadIdx.x;
  float s = 0.f;
  for (int k = 0; k < A1B / 16; ++k)
    s += part[((size_t)r * (A1B / 16) + k) * 256 + t];
  partA[r * 256 + t] = s;
}

// final: 128 threads -> scale/shift
__global__ __launch_bounds__(128) void bn_final_kernel(const float* __restrict__ partA,
    const float* __restrict__ gamma, const float* __restrict__ beta,
    float* __restrict__ scale, float* __restrict__ shift) {
  int c = threadIdx.x;
  float S = 0.f, Q = 0.f;
  for (int r = 0; r < 16; ++r) {
    S += partA[r * 256 + c];
    Q += partA[r * 256 + 128 + c];
  }
  float mean = S * (1.0f / GN);
  float var = Q * (1.0f / GN) - mean * mean;
  float istd = rsqrtf(var + 1e-5f);
  float g = gamma[c] * istd;
  scale[c] = g;
  shift[c] = beta[c] - mean * g;
}

// agg2: wave-per-node bf16 gather (ushort/lane), 8x unrolled; fp32 out
__global__ __launch_bounds__(256) void agg2_kernel(const unsigned short* __restrict__ h2b,
    const int* __restrict__ row, const int* __restrict__ srcs,
    const float* __restrict__ dinv, const float* __restrict__ b2,
    float* __restrict__ out) {
  int wave = (blockIdx.x * 256 + threadIdx.x) >> 6;
  int lane = threadIdx.x & 63;
  if (wave >= GN) return;
  int d = wave;
  float di = dinv[d];
  float acc = di * __uint_as_float(((unsigned)h2b[(size_t)d * 64 + lane]) << 16);
  int e0 = row[d], e1 = row[d + 1];
  int i = e0;
  for (; i + 8 <= e1; i += 8) {
    int s0 = srcs[i],     s1 = srcs[i + 1], s2 = srcs[i + 2], s3 = srcs[i + 3];
    int s4 = srcs[i + 4], s5 = srcs[i + 5], s6 = srcs[i + 6], s7 = srcs[i + 7];
    float w0 = dinv[s0], w1 = dinv[s1], w2 = dinv[s2], w3 = dinv[s3];
    float w4 = dinv[s4], w5 = dinv[s5], w6 = dinv[s6], w7 = dinv[s7];
    float v0 = __uint_as_float(((unsigned)h2b[(size_t)s0 * 64 + lane]) << 16);
    float v1 = __uint_as_float(((unsigned)h2b[(size_t)s1 * 64 + lane]) << 16);
    float v2 = __uint_as_float(((unsigned)h2b[(size_t)s2 * 64 + lane]) << 16);
    float v3 = __uint_as_float(((unsigned)h2b[(size_t)s3 * 64 + lane]) << 16);
    float v4 = __uint_as_float(((unsigned)h2b[(size_t)s4 * 64 + lane]) << 16);
    float v5 = __uint_as_float(((unsigned)h2b[(size_t)s5 * 64 + lane]) << 16);
    float v6 = __uint_as_float(((unsigned)h2b[(size_t)s6 * 64 + lane]) << 16);
    float v7 = __uint_as_float(((unsigned)h2b[(size_t)s7 * 64 + lane]) << 16);
    acc += w0 * v0 + w1 * v1 + w2 * v2 + w3 * v3;
    acc += w4 * v4 + w5 * v5 + w6 * v6 + w7 * v7;
  }
  for (; i < e1; ++i) {
    int s = srcs[i];
    acc += dinv[s] * __uint_as_float(((unsigned)h2b[(size_t)s * 64 + lane]) << 16);
  }
  out[(size_t)d * 64 + lane] = acc * di + b2[lane];
}

extern "C" void kernel_launch(void* const* d_in, const int* in_sizes, int n_in,
                              void* d_out, int out_size, void* d_ws, size_t ws_size,
                              hipStream_t stream) {
  const float* x     = (const float*)d_in[0];
  const int*   e1    = (const int*)d_in[1];
  const int*   e2    = (const int*)d_in[2];
  const float* W1    = (const float*)d_in[3];
  const float* b1    = (const float*)d_in[4];
  const float* gamma = (const float*)d_in[5];
  const float* beta  = (const float*)d_in[6];
  const float* W2    = (const float*)d_in[7];
  const float* b2    = (const float*)d_in[8];

  float* out    = (float*)d_out;               // [N,64]
  float* hidden = out + (size_t)GN * OUTC;     // [N,128] second tuple element

  float*          ws    = (float*)d_ws;
  unsigned*       h1b   = (unsigned*)(ws + OFF_H1);
  unsigned*       h2b   = (unsigned*)(ws + OFF_H2);
  float*          dinv1 = ws + OFF_DINV1;
  float*          dinv2 = ws + OFF_DINV2;
  int*            row1  = (int*)(ws + OFF_ROW1);
  int*            row2  = (int*)(ws + OFF_ROW2);
  int*            hist  = (int*)(ws + OFF_HIST);
  int*            tot   = (int*)(ws + OFF_TOT);
  int*            bbase = (int*)(ws + OFF_BBASE);
  float*          bnbuf = ws + OFF_BN;         // scale@0, shift@128
  float*          part  = ws + OFF_PART;
  float*          partA = ws + OFF_PARTA;
  int*            src1  = (int*)(ws + OFF_SRC1);
  int*            src2  = (int*)(ws + OFF_SRC2);
  // packed pair buffers alias h2b region: consumed (p2sort) before gemm2 writes h2b
  int*            pb1   = (int*)h2b;
  int*            pb2   = pb1 + GE;

  p1hist_kernel<<<dim3(NW, 2), 256, 0, stream>>>(e1, e2, hist);
  histscanA_kernel<<<dim3(NBK, 2), 256, 0, stream>>>(hist, tot);
  histscanB_kernel<<<1, 256, 0, stream>>>(tot, bbase);
  p1scat_kernel<<<dim3(NW, 2), 256, 0, stream>>>(e1, e2, hist, bbase, pb1, pb2);
  p2sort_kernel<<<dim3(NBK, 2), 256, 0, stream>>>(pb1, pb2, bbase,
                                                  row1, row2, dinv1, dinv2, src1, src2);

  gemm1_kernel<<<dim3((GN + 31) / 32, 2), 256, 0, stream>>>(x, W1, h1b);
  agg1_kernel<<<A1B, 256, 0, stream>>>(h1b, row1, src1, dinv1, b1, hidden, part);

  bn_reduceA_kernel<<<16, 256, 0, stream>>>(part, partA);
  bn_final_kernel<<<1, 128, 0, stream>>>(partA, gamma, beta, bnbuf, bnbuf + 128);

  gemm2_kernel<<<dim3((GN + 31) / 32, 1), 256, 0, stream>>>(hidden, W2,
                                                            bnbuf, bnbuf + 128, h2b);
  agg2_kernel<<<(GN * 64 + 255) / 256, 256, 0, stream>>>(
      (const unsigned short*)h2b, row2, src2, dinv2, b2, out);
}

// Round 10
// 275.919 us; speedup vs baseline: 2.3331x; 1.0629x over previous
//
#include <hip/hip_runtime.h>

#define GN 50000      // nodes
#define GE 800000     // edges per graph
#define HID 128
#define OUTC 64
#define NBK 196       // buckets of 256 nodes: ceil(50000/256)
#define NW  196       // WGs per graph in pass 1: ceil(800000/4096)
#define EPW 4096      // edges per WG
#define PCAP 5888     // p2sort stage capacity (bucket mean 4082, sd ~64)
#define A1B 2048      // agg1 blocks (grid-stride, 8192 waves)

// workspace layout (float element offsets)
#define OFF_H1    0            // h1 bf16 (pre-scaled by dinv1): GN*128 ushort
#define OFF_H2    3200000      // h2 bf16 (pre-scaled by dinv2): GN*64 ushort -- aliased: pb
#define OFF_DINV1 4800000      // 50,000
#define OFF_DINV2 4850000      // 50,000
#define OFF_ROW1  4900000      // 50,001 int
#define OFF_ROW2  4950004      // 50,001 int
#define OFF_HIST  5000008      // 2*NW*NBK = 76,832 int
#define OFF_TOT   5076840      // 2*NBK int
#define OFF_BBASE 5077232      // 2*(NBK+1) int
#define OFF_BN    5077632      // 512 f: scale@0 shift@128
#define OFF_PART  5078144      // A1B*256 f = 524,288
#define OFF_PARTA 5602432      // 16*256 f
#define OFF_SRC1  5606528      // 800,000 int (base byte offset 16B-aligned)
#define OFF_SRC2  6406528      // 800,000 int

__device__ inline unsigned bf16rne(float f) {
  unsigned u = __float_as_uint(f);
  return (u + 0x7FFFu + ((u >> 16) & 1u)) >> 16;
}
__device__ inline unsigned pack2(float a, float b) {
  return bf16rne(a) | (bf16rne(b) << 16);
}
__device__ inline float bflo(unsigned w) { return __uint_as_float(w << 16); }
__device__ inline float bfhi(unsigned w) { return __uint_as_float(w & 0xFFFF0000u); }
__device__ inline float bfs(unsigned short w) { return __uint_as_float(((unsigned)w) << 16); }

// ---------------- CSR build: LDS counting sort (unchanged) ----------------
__global__ __launch_bounds__(256) void p1hist_kernel(const int* __restrict__ e1,
    const int* __restrict__ e2, int* __restrict__ hist) {
  __shared__ int h[NBK];
  int g = blockIdx.y, w = blockIdx.x;
  const int* dst = (g ? e2 : e1) + GE;
  for (int i = threadIdx.x; i < NBK; i += 256) h[i] = 0;
  __syncthreads();
  int i0 = w * EPW, iend = i0 + EPW; if (iend > GE) iend = GE;
  for (int i = i0 + threadIdx.x; i < iend; i += 256)
    atomicAdd(&h[dst[i] >> 8], 1);
  __syncthreads();
  int* out = hist + ((size_t)g * NW + w) * NBK;
  for (int i = threadIdx.x; i < NBK; i += 256) out[i] = h[i];
}

__global__ __launch_bounds__(256) void histscanA_kernel(int* __restrict__ hist,
    int* __restrict__ tot) {
  __shared__ int lds[256];
  int b = blockIdx.x, g = blockIdx.y, t = threadIdx.x;
  int* col = hist + (size_t)g * NW * NBK + b;
  int v = (t < NW) ? col[(size_t)t * NBK] : 0;
  lds[t] = v;
  __syncthreads();
  for (int off = 1; off < 256; off <<= 1) {
    int u = (t >= off) ? lds[t - off] : 0;
    __syncthreads();
    lds[t] += u;
    __syncthreads();
  }
  if (t < NW) col[(size_t)t * NBK] = lds[t] - v;
  if (t == NW - 1) tot[g * NBK + b] = lds[t];
}

__global__ __launch_bounds__(256) void histscanB_kernel(const int* __restrict__ tot,
    int* __restrict__ bbase) {
  __shared__ int lds[256];
  int t = threadIdx.x;
  for (int g = 0; g < 2; ++g) {
    int v = (t < NBK) ? tot[g * NBK + t] : 0;
    int orig = v;
    lds[t] = v;
    __syncthreads();
    for (int off = 1; off < 256; off <<= 1) {
      int u = (t >= off) ? lds[t - off] : 0;
      __syncthreads();
      lds[t] += u;
      __syncthreads();
    }
    if (t < NBK) bbase[g * (NBK + 1) + t] = lds[t] - orig;
    if (t == NBK - 1) bbase[g * (NBK + 1) + NBK] = lds[t];
    __syncthreads();
  }
}

__global__ __launch_bounds__(256) void p1scat_kernel(const int* __restrict__ e1,
    const int* __restrict__ e2, const int* __restrict__ hist,
    const int* __restrict__ bbase, int* __restrict__ pb1, int* __restrict__ pb2) {
  __shared__ int off[NBK];
  int g = blockIdx.y, w = blockIdx.x;
  const int* e = g ? e2 : e1;
  int* pb = g ? pb2 : pb1;
  const int* hrow = hist + ((size_t)g * NW + w) * NBK;
  const int* bb = bbase + g * (NBK + 1);
  for (int i = threadIdx.x; i < NBK; i += 256) off[i] = bb[i] + hrow[i];
  __syncthreads();
  int i0 = w * EPW, iend = i0 + EPW; if (iend > GE) iend = GE;
  for (int i = i0 + threadIdx.x; i < iend; i += 256) {
    int d = e[GE + i], s = e[i];
    int p = atomicAdd(&off[d >> 8], 1);
    pb[p] = s | ((d & 255) << 16);
  }
}

__global__ __launch_bounds__(256) void p2sort_kernel(const int* __restrict__ pb1,
    const int* __restrict__ pb2, const int* __restrict__ bbase,
    int* __restrict__ row1, int* __restrict__ row2,
    float* __restrict__ dinv1, float* __restrict__ dinv2,
    int* __restrict__ src1, int* __restrict__ src2) {
  __shared__ int stage[PCAP];
  __shared__ int lcnt[256], lc2[256], arr[256];
  __shared__ int lrow[257];
  int g = blockIdx.y, b = blockIdx.x, t = threadIdx.x;
  const int* pb = g ? pb2 : pb1;
  const int* bb = bbase + g * (NBK + 1);
  int* row = g ? row2 : row1;
  float* dinv = g ? dinv2 : dinv1;
  int* src = g ? src2 : src1;
  int lo = b << 8, hi = lo + 256; if (hi > GN) hi = GN;
  int nn = hi - lo;
  int base = bb[b], end = bb[b + 1], L = end - base;
  lcnt[t] = 0; lc2[t] = 0;
  __syncthreads();
  for (int i = base + t; i < end; i += 256)
    atomicAdd(&lcnt[((unsigned)pb[i]) >> 16], 1);
  __syncthreads();
  int v = lcnt[t];
  arr[t] = v;
  __syncthreads();
  for (int off = 1; off < 256; off <<= 1) {
    int u = (t >= off) ? arr[t - off] : 0;
    __syncthreads();
    arr[t] += u;
    __syncthreads();
  }
  lrow[t] = arr[t] - v;
  if (t == 255) lrow[256] = arr[255];
  __syncthreads();
  if (t < nn) {
    row[lo + t] = base + lrow[t];
    dinv[lo + t] = rsqrtf(1.0f + (float)lcnt[t]);
  }
  if (b == NBK - 1 && t == 0) row[GN] = end;
  if (L <= PCAP) {
    for (int i = base + t; i < end; i += 256) {
      unsigned p = (unsigned)pb[i];
      int ld = p >> 16;
      int rk = atomicAdd(&lc2[ld], 1);
      stage[lrow[ld] + rk] = (int)(p & 0xFFFFu);
    }
    __syncthreads();
    for (int i = t; i < L; i += 256) src[base + i] = stage[i];
  } else {
    for (int i = base + t; i < end; i += 256) {
      unsigned p = (unsigned)pb[i];
      int ld = p >> 16;
      int rk = atomicAdd(&lc2[ld], 1);
      src[base + lrow[ld] + rk] = (int)(p & 0xFFFFu);
    }
  }
}

// ---------------- GEMMs (bf16 packed, dinv-prescaled output) ----------------
// h1b[r](bf16) = dinv1[r] * (A[r,:] @ B)   [N,128]
__global__ __launch_bounds__(256) void gemm1_kernel(const float* __restrict__ A,
    const float* __restrict__ B, const float* __restrict__ dinv1,
    unsigned* __restrict__ h1b) {
  __shared__ __align__(16) float wlds[128 * 64];
  __shared__ __align__(16) float alds[32 * 128];
  int t = threadIdx.x;
  int row0 = blockIdx.x * 32;
  int cb = blockIdx.y * 64;
  for (int i = t; i < 128 * 16; i += 256) {
    int k = i >> 4, c4 = i & 15;
    ((float4*)wlds)[i] = ((const float4*)B)[k * 32 + (cb >> 2) + c4];
  }
  for (int i = t; i < 1024; i += 256) {
    int r = i >> 5, c4 = i & 31;
    int gr = row0 + r;
    ((float4*)alds)[i] = (gr < GN) ? ((const float4*)A)[(size_t)gr * 32 + c4]
                                   : make_float4(0.f, 0.f, 0.f, 0.f);
  }
  __syncthreads();
  int j0 = (t & 15) * 4;
  int r0 = (t >> 4) * 2;
  float4 acc0 = {0, 0, 0, 0}, acc1 = {0, 0, 0, 0};
  #pragma unroll 8
  for (int k = 0; k < 128; ++k) {
    float4 w = *(const float4*)&wlds[k * 64 + j0];
    float a0 = alds[r0 * 128 + k];
    float a1 = alds[(r0 + 1) * 128 + k];
    acc0.x += a0 * w.x; acc0.y += a0 * w.y; acc0.z += a0 * w.z; acc0.w += a0 * w.w;
    acc1.x += a1 * w.x; acc1.y += a1 * w.y; acc1.z += a1 * w.z; acc1.w += a1 * w.w;
  }
  int gr0 = row0 + r0;
  if (gr0 < GN) {
    float dv = dinv1[gr0];
    uint2 p = make_uint2(pack2(dv * acc0.x, dv * acc0.y), pack2(dv * acc0.z, dv * acc0.w));
    ((uint2*)h1b)[((size_t)gr0 * 128 + cb + j0) >> 2] = p;
  }
  if (gr0 + 1 < GN) {
    float dv = dinv1[gr0 + 1];
    uint2 p = make_uint2(pack2(dv * acc1.x, dv * acc1.y), pack2(dv * acc1.z, dv * acc1.w));
    ((uint2*)h1b)[((size_t)(gr0 + 1) * 128 + cb + j0) >> 2] = p;
  }
}

// h2b[r](bf16) = dinv2[r] * (relu(bn(hidden[r,:])) @ B)   [N,64]
__global__ __launch_bounds__(256) void gemm2_kernel(const float* __restrict__ A,
    const float* __restrict__ B, const float* __restrict__ scale,
    const float* __restrict__ shift, const float* __restrict__ dinv2,
    unsigned* __restrict__ h2b) {
  __shared__ __align__(16) float wlds[128 * 64];
  __shared__ __align__(16) float alds[32 * 128];
  __shared__ float sc[128], sh[128];
  int t = threadIdx.x;
  if (t < 128) { sc[t] = scale[t]; sh[t] = shift[t]; }
  int row0 = blockIdx.x * 32;
  for (int i = t; i < 128 * 16; i += 256)
    ((float4*)wlds)[i] = ((const float4*)B)[i];
  __syncthreads();
  for (int i = t; i < 1024; i += 256) {
    int r = i >> 5, c4 = i & 31;
    int gr = row0 + r;
    float4 v = (gr < GN) ? ((const float4*)A)[(size_t)gr * 32 + c4]
                         : make_float4(0.f, 0.f, 0.f, 0.f);
    int c = c4 * 4;
    v.x = fmaxf(fmaf(v.x, sc[c],     sh[c]),     0.f);
    v.y = fmaxf(fmaf(v.y, sc[c + 1], sh[c + 1]), 0.f);
    v.z = fmaxf(fmaf(v.z, sc[c + 2], sh[c + 2]), 0.f);
    v.w = fmaxf(fmaf(v.w, sc[c + 3], sh[c + 3]), 0.f);
    ((float4*)alds)[i] = v;
  }
  __syncthreads();
  int j0 = (t & 15) * 4;
  int r0 = (t >> 4) * 2;
  float4 acc0 = {0, 0, 0, 0}, acc1 = {0, 0, 0, 0};
  #pragma unroll 8
  for (int k = 0; k < 128; ++k) {
    float4 w = *(const float4*)&wlds[k * 64 + j0];
    float a0 = alds[r0 * 128 + k];
    float a1 = alds[(r0 + 1) * 128 + k];
    acc0.x += a0 * w.x; acc0.y += a0 * w.y; acc0.z += a0 * w.z; acc0.w += a0 * w.w;
    acc1.x += a1 * w.x; acc1.y += a1 * w.y; acc1.z += a1 * w.z; acc1.w += a1 * w.w;
  }
  int gr0 = row0 + r0;
  if (gr0 < GN) {
    float dv = dinv2[gr0];
    uint2 p = make_uint2(pack2(dv * acc0.x, dv * acc0.y), pack2(dv * acc0.z, dv * acc0.w));
    ((uint2*)h2b)[((size_t)gr0 * 64 + j0) >> 2] = p;
  }
  if (gr0 + 1 < GN) {
    float dv = dinv2[gr0 + 1];
    uint2 p = make_uint2(pack2(dv * acc1.x, dv * acc1.y), pack2(dv * acc1.z, dv * acc1.w));
    ((uint2*)h2b)[((size_t)(gr0 + 1) * 64 + j0) >> 2] = p;
  }
}

// ---------------- Aggregations (pre-scaled rows: pure adds) ----------------
// hidden[d] = dinv[d]*(h1b[d] + sum_{s->d} h1b[s]) + b1 ; fused BN partials
__global__ __launch_bounds__(256) void agg1_kernel(const unsigned* __restrict__ h1b,
    const int* __restrict__ row, const int* __restrict__ srcs,
    const float* __restrict__ dinv, const float* __restrict__ b1,
    float* __restrict__ hidden, float* __restrict__ part) {
  __shared__ float ps[256];
  int t = threadIdx.x;
  int lane = t & 63;
  float2 b = ((const float2*)b1)[lane];
  float sx = 0.f, sy = 0.f, qx = 0.f, qy = 0.f;
  int wid = (blockIdx.x * 256 + t) >> 6;
  for (int d = wid; d < GN; d += A1B * 4) {
    float di = dinv[d];
    unsigned sw = h1b[(size_t)d * 64 + lane];
    float ax = bflo(sw), ay = bfhi(sw);   // self term already dinv-scaled
    int e0 = row[d], e1 = row[d + 1];
    int i = e0;
    while ((i & 3) && i < e1) {           // peel to 16B alignment of srcs
      unsigned v = h1b[(size_t)srcs[i] * 64 + lane];
      ax += bflo(v); ay += bfhi(v);
      ++i;
    }
    for (; i + 8 <= e1; i += 8) {
      int4 sa = *(const int4*)&srcs[i];
      int4 sb = *(const int4*)&srcs[i + 4];
      unsigned v0 = h1b[(size_t)sa.x * 64 + lane], v1 = h1b[(size_t)sa.y * 64 + lane];
      unsigned v2 = h1b[(size_t)sa.z * 64 + lane], v3 = h1b[(size_t)sa.w * 64 + lane];
      unsigned v4 = h1b[(size_t)sb.x * 64 + lane], v5 = h1b[(size_t)sb.y * 64 + lane];
      unsigned v6 = h1b[(size_t)sb.z * 64 + lane], v7 = h1b[(size_t)sb.w * 64 + lane];
      ax += bflo(v0); ay += bfhi(v0);
      ax += bflo(v1); ay += bfhi(v1);
      ax += bflo(v2); ay += bfhi(v2);
      ax += bflo(v3); ay += bfhi(v3);
      ax += bflo(v4); ay += bfhi(v4);
      ax += bflo(v5); ay += bfhi(v5);
      ax += bflo(v6); ay += bfhi(v6);
      ax += bflo(v7); ay += bfhi(v7);
    }
    if (i + 4 <= e1) {
      int4 sa = *(const int4*)&srcs[i];
      unsigned v0 = h1b[(size_t)sa.x * 64 + lane], v1 = h1b[(size_t)sa.y * 64 + lane];
      unsigned v2 = h1b[(size_t)sa.z * 64 + lane], v3 = h1b[(size_t)sa.w * 64 + lane];
      ax += bflo(v0); ay += bfhi(v0);
      ax += bflo(v1); ay += bfhi(v1);
      ax += bflo(v2); ay += bfhi(v2);
      ax += bflo(v3); ay += bfhi(v3);
      i += 4;
    }
    for (; i < e1; ++i) {
      unsigned v = h1b[(size_t)srcs[i] * 64 + lane];
      ax += bflo(v); ay += bfhi(v);
    }
    float ox = ax * di + b.x, oy = ay * di + b.y;
    float2 o; o.x = ox; o.y = oy;
    ((float2*)(hidden + (size_t)d * 128))[lane] = o;
    sx += ox; sy += oy; qx += ox * ox; qy += oy * oy;
  }
  float* pout = part + (size_t)blockIdx.x * 256;
  ps[t] = sx; __syncthreads();
  if (t < 64) pout[2 * t] = ps[t] + ps[t + 64] + ps[t + 128] + ps[t + 192];
  __syncthreads();
  ps[t] = sy; __syncthreads();
  if (t < 64) pout[2 * t + 1] = ps[t] + ps[t + 64] + ps[t + 128] + ps[t + 192];
  __syncthreads();
  ps[t] = qx; __syncthreads();
  if (t < 64) pout[128 + 2 * t] = ps[t] + ps[t + 64] + ps[t + 128] + ps[t + 192];
  __syncthreads();
  ps[t] = qy; __syncthreads();
  if (t < 64) pout[128 + 2 * t + 1] = ps[t] + ps[t + 64] + ps[t + 128] + ps[t + 192];
}

__global__ __launch_bounds__(256) void bn_reduceA_kernel(const float* __restrict__ part,
    float* __restrict__ partA) {
  int r = blockIdx.x, t = threadIdx.x;
  float s = 0.f;
  for (int k = 0; k < A1B / 16; ++k)
    s += part[((size_t)r * (A1B / 16) + k) * 256 + t];
  partA[r * 256 + t] = s;
}

__global__ __launch_bounds__(128) void bn_final_kernel(const float* __restrict__ partA,
    const float* __restrict__ gamma, const float* __restrict__ beta,
    float* __restrict__ scale, float* __restrict__ shift) {
  int c = threadIdx.x;
  float S = 0.f, Q = 0.f;
  for (int r = 0; r < 16; ++r) {
    S += partA[r * 256 + c];
    Q += partA[r * 256 + 128 + c];
  }
  float mean = S * (1.0f / GN);
  float var = Q * (1.0f / GN) - mean * mean;
  float istd = rsqrtf(var + 1e-5f);
  float g = gamma[c] * istd;
  scale[c] = g;
  shift[c] = beta[c] - mean * g;
}

// out[d] = dinv2[d]*(h2b[d] + sum h2b[s]) + b2
__global__ __launch_bounds__(256) void agg2_kernel(const unsigned short* __restrict__ h2b,
    const int* __restrict__ row, const int* __restrict__ srcs,
    const float* __restrict__ dinv, const float* __restrict__ b2,
    float* __restrict__ out) {
  int wave = (blockIdx.x * 256 + threadIdx.x) >> 6;
  int lane = threadIdx.x & 63;
  if (wave >= GN) return;
  int d = wave;
  float di = dinv[d];
  float acc = bfs(h2b[(size_t)d * 64 + lane]);
  int e0 = row[d], e1 = row[d + 1];
  int i = e0;
  while ((i & 3) && i < e1) {
    acc += bfs(h2b[(size_t)srcs[i] * 64 + lane]);
    ++i;
  }
  for (; i + 8 <= e1; i += 8) {
    int4 sa = *(const int4*)&srcs[i];
    int4 sb = *(const int4*)&srcs[i + 4];
    float v0 = bfs(h2b[(size_t)sa.x * 64 + lane]), v1 = bfs(h2b[(size_t)sa.y * 64 + lane]);
    float v2 = bfs(h2b[(size_t)sa.z * 64 + lane]), v3 = bfs(h2b[(size_t)sa.w * 64 + lane]);
    float v4 = bfs(h2b[(size_t)sb.x * 64 + lane]), v5 = bfs(h2b[(size_t)sb.y * 64 + lane]);
    float v6 = bfs(h2b[(size_t)sb.z * 64 + lane]), v7 = bfs(h2b[(size_t)sb.w * 64 + lane]);
    acc += v0 + v1 + v2 + v3 + v4 + v5 + v6 + v7;
  }
  if (i + 4 <= e1) {
    int4 sa = *(const int4*)&srcs[i];
    acc += bfs(h2b[(size_t)sa.x * 64 + lane]) + bfs(h2b[(size_t)sa.y * 64 + lane])
         + bfs(h2b[(size_t)sa.z * 64 + lane]) + bfs(h2b[(size_t)sa.w * 64 + lane]);
    i += 4;
  }
  for (; i < e1; ++i)
    acc += bfs(h2b[(size_t)srcs[i] * 64 + lane]);
  out[(size_t)d * 64 + lane] = acc * di + b2[lane];
}

extern "C" void kernel_launch(void* const* d_in, const int* in_sizes, int n_in,
                              void* d_out, int out_size, void* d_ws, size_t ws_size,
                              hipStream_t stream) {
  const float* x     = (const float*)d_in[0];
  const int*   e1    = (const int*)d_in[1];
  const int*   e2    = (const int*)d_in[2];
  const float* W1    = (const float*)d_in[3];
  const float* b1    = (const float*)d_in[4];
  const float* gamma = (const float*)d_in[5];
  const float* beta  = (const float*)d_in[6];
  const float* W2    = (const float*)d_in[7];
  const float* b2    = (const float*)d_in[8];

  float* out    = (float*)d_out;               // [N,64]
  float* hidden = out + (size_t)GN * OUTC;     // [N,128] second tuple element

  float*          ws    = (float*)d_ws;
  unsigned*       h1b   = (unsigned*)(ws + OFF_H1);
  unsigned*       h2b   = (unsigned*)(ws + OFF_H2);
  float*          dinv1 = ws + OFF_DINV1;
  float*          dinv2 = ws + OFF_DINV2;
  int*            row1  = (int*)(ws + OFF_ROW1);
  int*            row2  = (int*)(ws + OFF_ROW2);
  int*            hist  = (int*)(ws + OFF_HIST);
  int*            tot   = (int*)(ws + OFF_TOT);
  int*            bbase = (int*)(ws + OFF_BBASE);
  float*          bnbuf = ws + OFF_BN;         // scale@0, shift@128
  float*          part  = ws + OFF_PART;
  float*          partA = ws + OFF_PARTA;
  int*            src1  = (int*)(ws + OFF_SRC1);
  int*            src2  = (int*)(ws + OFF_SRC2);
  // packed pair buffers alias h2b region: consumed (p2sort) before gemm2 writes h2b
  int*            pb1   = (int*)h2b;
  int*            pb2   = pb1 + GE;

  p1hist_kernel<<<dim3(NW, 2), 256, 0, stream>>>(e1, e2, hist);
  histscanA_kernel<<<dim3(NBK, 2), 256, 0, stream>>>(hist, tot);
  histscanB_kernel<<<1, 256, 0, stream>>>(tot, bbase);
  p1scat_kernel<<<dim3(NW, 2), 256, 0, stream>>>(e1, e2, hist, bbase, pb1, pb2);
  p2sort_kernel<<<dim3(NBK, 2), 256, 0, stream>>>(pb1, pb2, bbase,
                                                  row1, row2, dinv1, dinv2, src1, src2);

  gemm1_kernel<<<dim3((GN + 31) / 32, 2), 256, 0, stream>>>(x, W1, dinv1, h1b);
  agg1_kernel<<<A1B, 256, 0, stream>>>(h1b, row1, src1, dinv1, b1, hidden, part);

  bn_reduceA_kernel<<<16, 256, 0, stream>>>(part, partA);
  bn_final_kernel<<<1, 128, 0, stream>>>(partA, gamma, beta, bnbuf, bnbuf + 128);

  gemm2_kernel<<<dim3((GN + 31) / 32, 1), 256, 0, stream>>>(hidden, W2,
                                                            bnbuf, bnbuf + 128, dinv2, h2b);
  agg2_kernel<<<(GN * 64 + 255) / 256, 256, 0, stream>>>(
      (const unsigned short*)h2b, row2, src2, dinv2, b2, out);
}

// Round 11
// 230.359 us; speedup vs baseline: 2.7945x; 1.1978x over previous
//
#include <hip/hip_runtime.h>

#define GN 50000      // nodes
#define GE 800000     // edges per graph
#define HID 128
#define OUTC 64
#define NBK 196       // buckets of 256 nodes
#define NW  196       // WGs per graph in pass 1
#define EPW 4096      // edges per WG
#define PCAP 5888     // p2sort stage capacity
#define A1B 2048      // agg1 blocks

// workspace layout (float element offsets)
#define OFF_H1    0            // h1 bf16 (pre-scaled by dinv1): GN*128 ushort
#define OFF_H2    3200000      // h2 bf16 (pre-scaled by dinv2) -- aliased: pb
#define OFF_DINV1 4800000
#define OFF_DINV2 4850000
#define OFF_ROW1  4900000
#define OFF_ROW2  4950004
#define OFF_HIST  5000008
#define OFF_TOT   5076840
#define OFF_BBASE 5077232
#define OFF_BN    5077632      // 512 f: scale@0 shift@128
#define OFF_PART  5078144      // A1B*256 f
#define OFF_PARTA 5602432      // 16*256 f
#define OFF_SRC1  5606528      // 800,000 int (16B-aligned)
#define OFF_SRC2  6406528      // 800,000 int
#define OFF_WT1   7206528      // 8192 uint (W1^T bf16: [n*64+k2])
#define OFF_WT2   7214720      // 4096 uint (W2^T bf16)

typedef __attribute__((ext_vector_type(8))) short bf16x8;
typedef __attribute__((ext_vector_type(4))) float f32x4;

__device__ inline unsigned bf16rne(float f) {
  unsigned u = __float_as_uint(f);
  return (u + 0x7FFFu + ((u >> 16) & 1u)) >> 16;
}
__device__ inline unsigned pack2(float a, float b) {
  return bf16rne(a) | (bf16rne(b) << 16);
}
__device__ inline float bflo(unsigned w) { return __uint_as_float(w << 16); }
__device__ inline float bfhi(unsigned w) { return __uint_as_float(w & 0xFFFF0000u); }
__device__ inline float bfs(unsigned short w) { return __uint_as_float(((unsigned)w) << 16); }

// ---------------- CSR build: LDS counting sort (unchanged) ----------------
__global__ __launch_bounds__(256) void p1hist_kernel(const int* __restrict__ e1,
    const int* __restrict__ e2, int* __restrict__ hist) {
  __shared__ int h[NBK];
  int g = blockIdx.y, w = blockIdx.x;
  const int* dst = (g ? e2 : e1) + GE;
  for (int i = threadIdx.x; i < NBK; i += 256) h[i] = 0;
  __syncthreads();
  int i0 = w * EPW, iend = i0 + EPW; if (iend > GE) iend = GE;
  for (int i = i0 + threadIdx.x; i < iend; i += 256)
    atomicAdd(&h[dst[i] >> 8], 1);
  __syncthreads();
  int* out = hist + ((size_t)g * NW + w) * NBK;
  for (int i = threadIdx.x; i < NBK; i += 256) out[i] = h[i];
}

__global__ __launch_bounds__(256) void histscanA_kernel(int* __restrict__ hist,
    int* __restrict__ tot) {
  __shared__ int lds[256];
  int b = blockIdx.x, g = blockIdx.y, t = threadIdx.x;
  int* col = hist + (size_t)g * NW * NBK + b;
  int v = (t < NW) ? col[(size_t)t * NBK] : 0;
  lds[t] = v;
  __syncthreads();
  for (int off = 1; off < 256; off <<= 1) {
    int u = (t >= off) ? lds[t - off] : 0;
    __syncthreads();
    lds[t] += u;
    __syncthreads();
  }
  if (t < NW) col[(size_t)t * NBK] = lds[t] - v;
  if (t == NW - 1) tot[g * NBK + b] = lds[t];
}

__global__ __launch_bounds__(256) void histscanB_kernel(const int* __restrict__ tot,
    int* __restrict__ bbase) {
  __shared__ int lds[256];
  int t = threadIdx.x;
  for (int g = 0; g < 2; ++g) {
    int v = (t < NBK) ? tot[g * NBK + t] : 0;
    int orig = v;
    lds[t] = v;
    __syncthreads();
    for (int off = 1; off < 256; off <<= 1) {
      int u = (t >= off) ? lds[t - off] : 0;
      __syncthreads();
      lds[t] += u;
      __syncthreads();
    }
    if (t < NBK) bbase[g * (NBK + 1) + t] = lds[t] - orig;
    if (t == NBK - 1) bbase[g * (NBK + 1) + NBK] = lds[t];
    __syncthreads();
  }
}

__global__ __launch_bounds__(256) void p1scat_kernel(const int* __restrict__ e1,
    const int* __restrict__ e2, const int* __restrict__ hist,
    const int* __restrict__ bbase, int* __restrict__ pb1, int* __restrict__ pb2) {
  __shared__ int off[NBK];
  int g = blockIdx.y, w = blockIdx.x;
  const int* e = g ? e2 : e1;
  int* pb = g ? pb2 : pb1;
  const int* hrow = hist + ((size_t)g * NW + w) * NBK;
  const int* bb = bbase + g * (NBK + 1);
  for (int i = threadIdx.x; i < NBK; i += 256) off[i] = bb[i] + hrow[i];
  __syncthreads();
  int i0 = w * EPW, iend = i0 + EPW; if (iend > GE) iend = GE;
  for (int i = i0 + threadIdx.x; i < iend; i += 256) {
    int d = e[GE + i], s = e[i];
    int p = atomicAdd(&off[d >> 8], 1);
    pb[p] = s | ((d & 255) << 16);
  }
}

__global__ __launch_bounds__(256) void p2sort_kernel(const int* __restrict__ pb1,
    const int* __restrict__ pb2, const int* __restrict__ bbase,
    int* __restrict__ row1, int* __restrict__ row2,
    float* __restrict__ dinv1, float* __restrict__ dinv2,
    int* __restrict__ src1, int* __restrict__ src2) {
  __shared__ int stage[PCAP];
  __shared__ int lcnt[256], lc2[256], arr[256];
  __shared__ int lrow[257];
  int g = blockIdx.y, b = blockIdx.x, t = threadIdx.x;
  const int* pb = g ? pb2 : pb1;
  const int* bb = bbase + g * (NBK + 1);
  int* row = g ? row2 : row1;
  float* dinv = g ? dinv2 : dinv1;
  int* src = g ? src2 : src1;
  int lo = b << 8, hi = lo + 256; if (hi > GN) hi = GN;
  int nn = hi - lo;
  int base = bb[b], end = bb[b + 1], L = end - base;
  lcnt[t] = 0; lc2[t] = 0;
  __syncthreads();
  for (int i = base + t; i < end; i += 256)
    atomicAdd(&lcnt[((unsigned)pb[i]) >> 16], 1);
  __syncthreads();
  int v = lcnt[t];
  arr[t] = v;
  __syncthreads();
  for (int off = 1; off < 256; off <<= 1) {
    int u = (t >= off) ? arr[t - off] : 0;
    __syncthreads();
    arr[t] += u;
    __syncthreads();
  }
  lrow[t] = arr[t] - v;
  if (t == 255) lrow[256] = arr[255];
  __syncthreads();
  if (t < nn) {
    row[lo + t] = base + lrow[t];
    dinv[lo + t] = rsqrtf(1.0f + (float)lcnt[t]);
  }
  if (b == NBK - 1 && t == 0) row[GN] = end;
  if (L <= PCAP) {
    for (int i = base + t; i < end; i += 256) {
      unsigned p = (unsigned)pb[i];
      int ld = p >> 16;
      int rk = atomicAdd(&lc2[ld], 1);
      stage[lrow[ld] + rk] = (int)(p & 0xFFFFu);
    }
    __syncthreads();
    for (int i = t; i < L; i += 256) src[base + i] = stage[i];
  } else {
    for (int i = base + t; i < end; i += 256) {
      unsigned p = (unsigned)pb[i];
      int ld = p >> 16;
      int rk = atomicAdd(&lc2[ld], 1);
      src[base + lrow[ld] + rk] = (int)(p & 0xFFFFu);
    }
  }
}

// ---------------- one-time weight convert/transpose to bf16 ----------------
// wt1[n*64 + k2] = pack2(W1[2k2][n], W1[2k2+1][n])   n<128, k2<64
// wt2[n*64 + k2] = pack2(W2[2k2][n], W2[2k2+1][n])   n<64
__global__ __launch_bounds__(256) void wcvt_kernel(const float* __restrict__ W1,
    const float* __restrict__ W2, unsigned* __restrict__ wt1, unsigned* __restrict__ wt2) {
  int t = blockIdx.x * 256 + threadIdx.x;
  if (t < 8192) {
    int n = t >> 6, k2 = t & 63;
    wt1[t] = pack2(W1[(2 * k2) * 128 + n], W1[(2 * k2 + 1) * 128 + n]);
  }
  if (t < 4096) {
    int n = t >> 6, k2 = t & 63;
    wt2[t] = pack2(W2[(2 * k2) * 64 + n], W2[(2 * k2 + 1) * 64 + n]);
  }
}

// ---------------- MFMA GEMMs ----------------
// h1u[r][c](bf16) = dinv1[r] * (x[r,:] @ W1)  via 16x16x32 bf16 MFMA
// block: 64 rows x 128 cols, 4 waves; wave w: rows 32*(w&1), cols 64*(w>>1)
__global__ __launch_bounds__(256) void gemm1_kernel(const float* __restrict__ A,
    const unsigned* __restrict__ wt1, const float* __restrict__ dinv1,
    unsigned short* __restrict__ h1u) {
  __shared__ unsigned a_lds[64 * 68];    // [m][k2] stride 68 words (136 ushort)
  __shared__ unsigned w_lds[128 * 68];   // [n][k2]
  int t = threadIdx.x;
  int row0 = blockIdx.x * 64;
  for (int i = t; i < 128 * 64; i += 256)
    w_lds[(i >> 6) * 68 + (i & 63)] = wt1[i];
  for (int i = t; i < 64 * 32; i += 256) {
    int m = i >> 5, k4 = i & 31;
    int gr = row0 + m;
    float4 v = (gr < GN) ? ((const float4*)A)[(size_t)gr * 32 + k4]
                         : make_float4(0.f, 0.f, 0.f, 0.f);
    unsigned* dst = &a_lds[m * 68 + k4 * 2];
    dst[0] = pack2(v.x, v.y);
    dst[1] = pack2(v.z, v.w);
  }
  __syncthreads();
  int lane = t & 63, w = t >> 6;
  int n16 = lane & 15, quad = lane >> 4;
  int mbase = (w & 1) * 32;
  int nbase = (w >> 1) * 64;
  f32x4 acc[2][4] = {};
  const unsigned short* als = (const unsigned short*)a_lds;
  const unsigned short* wls = (const unsigned short*)w_lds;
  #pragma unroll
  for (int ks = 0; ks < 4; ++ks) {
    int k0 = ks * 32 + quad * 8;
    bf16x8 a0 = *(const bf16x8*)(als + (mbase + n16) * 136 + k0);
    bf16x8 a1 = *(const bf16x8*)(als + (mbase + 16 + n16) * 136 + k0);
    #pragma unroll
    for (int nt = 0; nt < 4; ++nt) {
      bf16x8 bf = *(const bf16x8*)(wls + (nbase + nt * 16 + n16) * 136 + k0);
      acc[0][nt] = __builtin_amdgcn_mfma_f32_16x16x32_bf16(a0, bf, acc[0][nt], 0, 0, 0);
      acc[1][nt] = __builtin_amdgcn_mfma_f32_16x16x32_bf16(a1, bf, acc[1][nt], 0, 0, 0);
    }
  }
  #pragma unroll
  for (int mt = 0; mt < 2; ++mt) {
    #pragma unroll
    for (int r = 0; r < 4; ++r) {
      int row_g = row0 + mbase + mt * 16 + quad * 4 + r;
      if (row_g < GN) {
        float dv = dinv1[row_g];
        #pragma unroll
        for (int nt = 0; nt < 4; ++nt) {
          int col = nbase + nt * 16 + n16;
          h1u[(size_t)row_g * 128 + col] = (unsigned short)bf16rne(dv * acc[mt][nt][r]);
        }
      }
    }
  }
}

// h2u[r][c](bf16) = dinv2[r] * (relu(bn(hidden[r,:])) @ W2)
// block: 64 rows x 64 cols, 4 waves; wave w: rows 16*w, all 64 cols
__global__ __launch_bounds__(256) void gemm2_kernel(const float* __restrict__ A,
    const unsigned* __restrict__ wt2, const float* __restrict__ scale,
    const float* __restrict__ shift, const float* __restrict__ dinv2,
    unsigned short* __restrict__ h2u) {
  __shared__ unsigned a_lds[64 * 68];
  __shared__ unsigned w_lds[64 * 68];
  __shared__ float sc[128], sh[128];
  int t = threadIdx.x;
  if (t < 128) { sc[t] = scale[t]; sh[t] = shift[t]; }
  int row0 = blockIdx.x * 64;
  for (int i = t; i < 64 * 64; i += 256)
    w_lds[(i >> 6) * 68 + (i & 63)] = wt2[i];
  __syncthreads();   // sc/sh ready
  for (int i = t; i < 64 * 32; i += 256) {
    int m = i >> 5, k4 = i & 31;
    int gr = row0 + m;
    float4 v = (gr < GN) ? ((const float4*)A)[(size_t)gr * 32 + k4]
                         : make_float4(0.f, 0.f, 0.f, 0.f);
    int c = k4 * 4;
    v.x = fmaxf(fmaf(v.x, sc[c],     sh[c]),     0.f);
    v.y = fmaxf(fmaf(v.y, sc[c + 1], sh[c + 1]), 0.f);
    v.z = fmaxf(fmaf(v.z, sc[c + 2], sh[c + 2]), 0.f);
    v.w = fmaxf(fmaf(v.w, sc[c + 3], sh[c + 3]), 0.f);
    unsigned* dst = &a_lds[m * 68 + k4 * 2];
    dst[0] = pack2(v.x, v.y);
    dst[1] = pack2(v.z, v.w);
  }
  __syncthreads();
  int lane = t & 63, w = t >> 6;
  int n16 = lane & 15, quad = lane >> 4;
  f32x4 acc[4] = {};
  const unsigned short* als = (const unsigned short*)a_lds;
  const unsigned short* wls = (const unsigned short*)w_lds;
  #pragma unroll
  for (int ks = 0; ks < 4; ++ks) {
    int k0 = ks * 32 + quad * 8;
    bf16x8 af = *(const bf16x8*)(als + (w * 16 + n16) * 136 + k0);
    #pragma unroll
    for (int nt = 0; nt < 4; ++nt) {
      bf16x8 bf = *(const bf16x8*)(wls + (nt * 16 + n16) * 136 + k0);
      acc[nt] = __builtin_amdgcn_mfma_f32_16x16x32_bf16(af, bf, acc[nt], 0, 0, 0);
    }
  }
  #pragma unroll
  for (int r = 0; r < 4; ++r) {
    int row_g = row0 + w * 16 + quad * 4 + r;
    if (row_g < GN) {
      float dv = dinv2[row_g];
      #pragma unroll
      for (int nt = 0; nt < 4; ++nt) {
        int col = nt * 16 + n16;
        h2u[(size_t)row_g * 64 + col] = (unsigned short)bf16rne(dv * acc[nt][r]);
      }
    }
  }
}

// ---------------- Aggregations (pre-scaled rows: pure adds) ----------------
__global__ __launch_bounds__(256) void agg1_kernel(const unsigned* __restrict__ h1b,
    const int* __restrict__ row, const int* __restrict__ srcs,
    const float* __restrict__ dinv, const float* __restrict__ b1,
    float* __restrict__ hidden, float* __restrict__ part) {
  __shared__ float ps[256];
  int t = threadIdx.x;
  int lane = t & 63;
  float2 b = ((const float2*)b1)[lane];
  float sx = 0.f, sy = 0.f, qx = 0.f, qy = 0.f;
  int wid = (blockIdx.x * 256 + t) >> 6;
  for (int d = wid; d < GN; d += A1B * 4) {
    float di = dinv[d];
    unsigned sw = h1b[(size_t)d * 64 + lane];
    float ax = bflo(sw), ay = bfhi(sw);
    int e0 = row[d], e1 = row[d + 1];
    int i = e0;
    while ((i & 3) && i < e1) {
      unsigned v = h1b[(size_t)srcs[i] * 64 + lane];
      ax += bflo(v); ay += bfhi(v);
      ++i;
    }
    for (; i + 8 <= e1; i += 8) {
      int4 sa = *(const int4*)&srcs[i];
      int4 sb = *(const int4*)&srcs[i + 4];
      unsigned v0 = h1b[(size_t)sa.x * 64 + lane], v1 = h1b[(size_t)sa.y * 64 + lane];
      unsigned v2 = h1b[(size_t)sa.z * 64 + lane], v3 = h1b[(size_t)sa.w * 64 + lane];
      unsigned v4 = h1b[(size_t)sb.x * 64 + lane], v5 = h1b[(size_t)sb.y * 64 + lane];
      unsigned v6 = h1b[(size_t)sb.z * 64 + lane], v7 = h1b[(size_t)sb.w * 64 + lane];
      ax += bflo(v0); ay += bfhi(v0);
      ax += bflo(v1); ay += bfhi(v1);
      ax += bflo(v2); ay += bfhi(v2);
      ax += bflo(v3); ay += bfhi(v3);
      ax += bflo(v4); ay += bfhi(v4);
      ax += bflo(v5); ay += bfhi(v5);
      ax += bflo(v6); ay += bfhi(v6);
      ax += bflo(v7); ay += bfhi(v7);
    }
    if (i + 4 <= e1) {
      int4 sa = *(const int4*)&srcs[i];
      unsigned v0 = h1b[(size_t)sa.x * 64 + lane], v1 = h1b[(size_t)sa.y * 64 + lane];
      unsigned v2 = h1b[(size_t)sa.z * 64 + lane], v3 = h1b[(size_t)sa.w * 64 + lane];
      ax += bflo(v0); ay += bfhi(v0);
      ax += bflo(v1); ay += bfhi(v1);
      ax += bflo(v2); ay += bfhi(v2);
      ax += bflo(v3); ay += bfhi(v3);
      i += 4;
    }
    for (; i < e1; ++i) {
      unsigned v = h1b[(size_t)srcs[i] * 64 + lane];
      ax += bflo(v); ay += bfhi(v);
    }
    float ox = ax * di + b.x, oy = ay * di + b.y;
    float2 o; o.x = ox; o.y = oy;
    ((float2*)(hidden + (size_t)d * 128))[lane] = o;
    sx += ox; sy += oy; qx += ox * ox; qy += oy * oy;
  }
  float* pout = part + (size_t)blockIdx.x * 256;
  ps[t] = sx; __syncthreads();
  if (t < 64) pout[2 * t] = ps[t] + ps[t + 64] + ps[t + 128] + ps[t + 192];
  __syncthreads();
  ps[t] = sy; __syncthreads();
  if (t < 64) pout[2 * t + 1] = ps[t] + ps[t + 64] + ps[t + 128] + ps[t + 192];
  __syncthreads();
  ps[t] = qx; __syncthreads();
  if (t < 64) pout[128 + 2 * t] = ps[t] + ps[t + 64] + ps[t + 128] + ps[t + 192];
  __syncthreads();
  ps[t] = qy; __syncthreads();
  if (t < 64) pout[128 + 2 * t + 1] = ps[t] + ps[t + 64] + ps[t + 128] + ps[t + 192];
}

__global__ __launch_bounds__(256) void bn_reduceA_kernel(const float* __restrict__ part,
    float* __restrict__ partA) {
  int r = blockIdx.x, t = threadIdx.x;
  float s = 0.f;
  for (int k = 0; k < A1B / 16; ++k)
    s += part[((size_t)r * (A1B / 16) + k) * 256 + t];
  partA[r * 256 + t] = s;
}

__global__ __launch_bounds__(128) void bn_final_kernel(const float* __restrict__ partA,
    const float* __restrict__ gamma, const float* __restrict__ beta,
    float* __restrict__ scale, float* __restrict__ shift) {
  int c = threadIdx.x;
  float S = 0.f, Q = 0.f;
  for (int r = 0; r < 16; ++r) {
    S += partA[r * 256 + c];
    Q += partA[r * 256 + 128 + c];
  }
  float mean = S * (1.0f / GN);
  float var = Q * (1.0f / GN) - mean * mean;
  float istd = rsqrtf(var + 1e-5f);
  float g = gamma[c] * istd;
  scale[c] = g;
  shift[c] = beta[c] - mean * g;
}

__global__ __launch_bounds__(256) void agg2_kernel(const unsigned short* __restrict__ h2b,
    const int* __restrict__ row, const int* __restrict__ srcs,
    const float* __restrict__ dinv, const float* __restrict__ b2,
    float* __restrict__ out) {
  int wave = (blockIdx.x * 256 + threadIdx.x) >> 6;
  int lane = threadIdx.x & 63;
  if (wave >= GN) return;
  int d = wave;
  float di = dinv[d];
  float acc = bfs(h2b[(size_t)d * 64 + lane]);
  int e0 = row[d], e1 = row[d + 1];
  int i = e0;
  while ((i & 3) && i < e1) {
    acc += bfs(h2b[(size_t)srcs[i] * 64 + lane]);
    ++i;
  }
  for (; i + 8 <= e1; i += 8) {
    int4 sa = *(const int4*)&srcs[i];
    int4 sb = *(const int4*)&srcs[i + 4];
    float v0 = bfs(h2b[(size_t)sa.x * 64 + lane]), v1 = bfs(h2b[(size_t)sa.y * 64 + lane]);
    float v2 = bfs(h2b[(size_t)sa.z * 64 + lane]), v3 = bfs(h2b[(size_t)sa.w * 64 + lane]);
    float v4 = bfs(h2b[(size_t)sb.x * 64 + lane]), v5 = bfs(h2b[(size_t)sb.y * 64 + lane]);
    float v6 = bfs(h2b[(size_t)sb.z * 64 + lane]), v7 = bfs(h2b[(size_t)sb.w * 64 + lane]);
    acc += v0 + v1 + v2 + v3 + v4 + v5 + v6 + v7;
  }
  if (i + 4 <= e1) {
    int4 sa = *(const int4*)&srcs[i];
    acc += bfs(h2b[(size_t)sa.x * 64 + lane]) + bfs(h2b[(size_t)sa.y * 64 + lane])
         + bfs(h2b[(size_t)sa.z * 64 + lane]) + bfs(h2b[(size_t)sa.w * 64 + lane]);
    i += 4;
  }
  for (; i < e1; ++i)
    acc += bfs(h2b[(size_t)srcs[i] * 64 + lane]);
  out[(size_t)d * 64 + lane] = acc * di + b2[lane];
}

extern "C" void kernel_launch(void* const* d_in, const int* in_sizes, int n_in,
                              void* d_out, int out_size, void* d_ws, size_t ws_size,
                              hipStream_t stream) {
  const float* x     = (const float*)d_in[0];
  const int*   e1    = (const int*)d_in[1];
  const int*   e2    = (const int*)d_in[2];
  const float* W1    = (const float*)d_in[3];
  const float* b1    = (const float*)d_in[4];
  const float* gamma = (const float*)d_in[5];
  const float* beta  = (const float*)d_in[6];
  const float* W2    = (const float*)d_in[7];
  const float* b2    = (const float*)d_in[8];

  float* out    = (float*)d_out;               // [N,64]
  float* hidden = out + (size_t)GN * OUTC;     // [N,128]

  float*          ws    = (float*)d_ws;
  unsigned*       h1b   = (unsigned*)(ws + OFF_H1);
  unsigned*       h2b   = (unsigned*)(ws + OFF_H2);
  float*          dinv1 = ws + OFF_DINV1;
  float*          dinv2 = ws + OFF_DINV2;
  int*            row1  = (int*)(ws + OFF_ROW1);
  int*            row2  = (int*)(ws + OFF_ROW2);
  int*            hist  = (int*)(ws + OFF_HIST);
  int*            tot   = (int*)(ws + OFF_TOT);
  int*            bbase = (int*)(ws + OFF_BBASE);
  float*          bnbuf = ws + OFF_BN;
  float*          part  = ws + OFF_PART;
  float*          partA = ws + OFF_PARTA;
  int*            src1  = (int*)(ws + OFF_SRC1);
  int*            src2  = (int*)(ws + OFF_SRC2);
  unsigned*       wt1   = (unsigned*)(ws + OFF_WT1);
  unsigned*       wt2   = (unsigned*)(ws + OFF_WT2);
  int*            pb1   = (int*)h2b;
  int*            pb2   = pb1 + GE;

  wcvt_kernel<<<32, 256, 0, stream>>>(W1, W2, wt1, wt2);
  p1hist_kernel<<<dim3(NW, 2), 256, 0, stream>>>(e1, e2, hist);
  histscanA_kernel<<<dim3(NBK, 2), 256, 0, stream>>>(hist, tot);
  histscanB_kernel<<<1, 256, 0, stream>>>(tot, bbase);
  p1scat_kernel<<<dim3(NW, 2), 256, 0, stream>>>(e1, e2, hist, bbase, pb1, pb2);
  p2sort_kernel<<<dim3(NBK, 2), 256, 0, stream>>>(pb1, pb2, bbase,
                                                  row1, row2, dinv1, dinv2, src1, src2);

  gemm1_kernel<<<(GN + 63) / 64, 256, 0, stream>>>(x, wt1, dinv1,
                                                   (unsigned short*)h1b);
  agg1_kernel<<<A1B, 256, 0, stream>>>(h1b, row1, src1, dinv1, b1, hidden, part);

  bn_reduceA_kernel<<<16, 256, 0, stream>>>(part, partA);
  bn_final_kernel<<<1, 128, 0, stream>>>(partA, gamma, beta, bnbuf, bnbuf + 128);

  gemm2_kernel<<<(GN + 63) / 64, 256, 0, stream>>>(hidden, wt2, bnbuf, bnbuf + 128,
                                                   dinv2, (unsigned short*)h2b);
  agg2_kernel<<<(GN * 64 + 255) / 256, 256, 0, stream>>>(
      (const unsigned short*)h2b, row2, src2, dinv2, b2, out);
}